// Round 1
// 496.502 us; speedup vs baseline: 1.1558x; 1.1558x over previous
//
#include <hip/hip_runtime.h>
#include <hip/hip_fp16.h>
#include <math.h>

#define N_NODES 50000
#define N_EDGES 1600000
#define D_IN 128
#define D_H 64
#define N_CLS 10
#define N_GRAPHS 64
#define NEG_SLOPE 0.2f
#define E2 (N_EDGES + N_NODES)   // edges + self loops
#define SCAN_BS 256
#define NBLK ((N_NODES + SCAN_BS - 1) / SCAN_BS)   // 196 <= 256

// bucketed scatter params
#define NB 25                 // buckets: dst >> 11 (50000/2048 -> 0..24)
#define BSH 11
#define CAP 76800             // per-bucket staging capacity (>40 sigma over E/NB)
#define CHUNKS (CAP / 256)    // 300 blocks per bucket in pass B
#define HBB 8                 // hist blocks per bucket
#define EPT 8                 // edges/thread in bucket_stage (was 4; atomic fix removes the
                              // block-count-proportional cost that made >4 look bad)
#define PAD 32                // 128B stride: one cache line per contended counter

__device__ inline float wave_reduce_sum(float v) {
    for (int off = 32; off; off >>= 1) v += __shfl_xor(v, off);
    return v;
}

// one 8B load -> 4 floats from fp16 row chunk
__device__ inline float4 ld_h4(const __half* p) {
    int2 raw = *(const int2*)p;
    __half2 a = *(__half2*)&raw.x;
    __half2 b = *(__half2*)&raw.y;
    return make_float4(__low2float(a), __high2float(a), __low2float(b), __high2float(b));
}

// ===== pass A: bucket-stage edges + eattr sum.
// Counter theory (r0): old version was serialized on same-line global atomics
// (6252 per-wave esum adds to ONE word + 39K bcursor adds to ONE 128B line) —
// VALUBusy 1%, HBM 4%, dur scaled linearly with block count. Fixes:
//   - esum: per-BLOCK reduce, spread over 32 distinct 128B lines
//   - bcursor: one 128B line per bucket (b*PAD)
//   - EPT 4->8: halves block count -> halves both atomic streams
//   - int2 staging: (src | dst_low11 << 16, eattr_bits) — bucket id is implied
//     by the staging address, so 11 low dst bits suffice. Halves stg traffic.
__global__ void bucket_stage(const int* __restrict__ src, const int* __restrict__ dst,
                             const float* __restrict__ eattr,
                             float* esum, int* bcursor,
                             int2* __restrict__ stg) {
    __shared__ int bcnt[4][32];
    __shared__ int woff[4][32];
    __shared__ float esh[4];
    int t = threadIdx.x;
    int wave = t >> 6;
    if (t < 128) bcnt[t >> 5][t & 31] = 0;
    __syncthreads();
    int e0 = (blockIdx.x * blockDim.x + t) * EPT;   // N_EDGES % EPT == 0
    int ss[EPT], tt[EPT], aa[EPT], r[EPT], b[EPT];
    float v = 0.f;
    bool valid = e0 < N_EDGES;
    if (valid) {
        #pragma unroll
        for (int q = 0; q < EPT / 4; ++q) {
            int4 s4 = *(const int4*)(src + e0 + 4 * q);
            int4 t4 = *(const int4*)(dst + e0 + 4 * q);
            float4 a4 = *(const float4*)(eattr + e0 + 4 * q);
            ss[4*q] = s4.x; ss[4*q+1] = s4.y; ss[4*q+2] = s4.z; ss[4*q+3] = s4.w;
            tt[4*q] = t4.x; tt[4*q+1] = t4.y; tt[4*q+2] = t4.z; tt[4*q+3] = t4.w;
            aa[4*q]   = __float_as_int(a4.x); aa[4*q+1] = __float_as_int(a4.y);
            aa[4*q+2] = __float_as_int(a4.z); aa[4*q+3] = __float_as_int(a4.w);
            v += (a4.x + a4.y) + (a4.z + a4.w);
        }
        #pragma unroll
        for (int i = 0; i < EPT; ++i) {
            b[i] = tt[i] >> BSH;
            r[i] = atomicAdd(&bcnt[wave][b[i]], 1);
        }
    }
    v = wave_reduce_sum(v);
    if ((t & 63) == 0) esh[wave] = v;
    __syncthreads();
    if (t < NB) {
        int c0 = bcnt[0][t], c1 = bcnt[1][t], c2 = bcnt[2][t], c3 = bcnt[3][t];
        int tot = c0 + c1 + c2 + c3;
        int base = tot ? atomicAdd(&bcursor[t * PAD], tot) : 0;
        woff[0][t] = base;
        woff[1][t] = base + c0;
        woff[2][t] = base + c0 + c1;
        woff[3][t] = base + c0 + c1 + c2;
    }
    if (t == 0) {
        float tot = (esh[0] + esh[1]) + (esh[2] + esh[3]);
        atomicAdd(&esum[(blockIdx.x & 31) * PAD], tot);   // 32 distinct lines
    }
    __syncthreads();
    if (valid) {
        #pragma unroll
        for (int i = 0; i < EPT; ++i) {
            int p = b[i] * CAP + woff[wave][b[i]] + r[i];
            stg[p] = make_int2((ss[i] & 0xFFFF) | ((tt[i] & 2047) << 16), aa[i]);
        }
    }
}

// ===== pass A2: per-node histogram from staged dst-low bits, LDS-resident window
__global__ void hist_bucket(const int2* __restrict__ stg, const int* __restrict__ bcursor,
                            int* cnt) {
    __shared__ int hist[2048];
    int b = blockIdx.x / HBB;
    int j = blockIdx.x % HBB;
    for (int i = threadIdx.x; i < 2048; i += 256) hist[i] = 0;
    __syncthreads();
    int n = bcursor[b * PAD];
    const int2* sd = stg + (size_t)b * CAP;
    int per = (n + HBB - 1) / HBB;
    int start = j * per;
    int end = min(start + per, n);
    for (int idx = start + threadIdx.x; idx < end; idx += 256)
        atomicAdd(&hist[(sd[idx].x >> 16) & 2047], 1);
    __syncthreads();
    int nb = b << BSH;
    for (int i = threadIdx.x; i < 2048; i += 256) {
        int c = hist[i];
        if (c) atomicAdd(&cnt[nb + i], c);
    }
}

// ---- block-local exclusive scan; +1 per node folds in the self-loop slot ----
__global__ void scan_block(const int* __restrict__ cnt, int* __restrict__ row_start,
                           int* __restrict__ partial) {
    __shared__ int sd[SCAN_BS];
    int i = blockIdx.x * SCAN_BS + threadIdx.x;
    int v = (i < N_NODES) ? (cnt[i] + 1) : 0;   // +1 = self loop
    sd[threadIdx.x] = v;
    __syncthreads();
    for (int off = 1; off < SCAN_BS; off <<= 1) {
        int t = (threadIdx.x >= off) ? sd[threadIdx.x - off] : 0;
        __syncthreads();
        sd[threadIdx.x] += t;
        __syncthreads();
    }
    if (i < N_NODES) row_start[i] = sd[threadIdx.x] - v;
    if (threadIdx.x == SCAN_BS - 1) partial[blockIdx.x] = sd[threadIdx.x];
}
// finalize row_start (redundant LDS scan of partials replaces a launch),
// write self-loop CSR entry, seed cursor
__global__ void add_offsets(int* __restrict__ row_start, const int* __restrict__ partial,
                            int* __restrict__ cursor, const float* __restrict__ esum,
                            int2* __restrict__ csr_pack) {
    __shared__ int sp[SCAN_BS];
    int pv = (threadIdx.x < NBLK) ? partial[threadIdx.x] : 0;
    sp[threadIdx.x] = pv;
    __syncthreads();
    for (int off = 1; off < SCAN_BS; off <<= 1) {
        int t = (threadIdx.x >= off) ? sp[threadIdx.x - off] : 0;
        __syncthreads();
        sp[threadIdx.x] += t;
        __syncthreads();
    }
    float es = 0.f;
    #pragma unroll
    for (int jj = 0; jj < 32; ++jj) es += esum[jj * PAD];
    int base = (blockIdx.x == 0) ? 0 : sp[blockIdx.x - 1];
    int i = blockIdx.x * SCAN_BS + threadIdx.x;
    if (i < N_NODES) {
        int r = row_start[i] + base;
        row_start[i] = r;
        csr_pack[r] = make_int2(i, __float_as_int(es * (1.0f / N_EDGES)));
        cursor[i] = r + 1;
    }
    if (i == 0) row_start[N_NODES] = E2;
}

// ===== pass B: scatter within buckets (L2-confined windows, XCD swizzle)
__global__ void scatter_bucketed(const int2* __restrict__ stg,
                                 const int* __restrict__ bcursor, int* cursor,
                                 int2* __restrict__ csr_pack) {
    int g = blockIdx.x;
    int xcd = g & 7;
    int k = g >> 3;
    int b = xcd + 8 * (k / CHUNKS);
    if (b >= NB) return;
    int j = k % CHUNKS;
    int n = bcursor[b * PAD];
    int idx = j * 256 + threadIdx.x;
    if (idx >= n) return;
    int2 e = stg[(size_t)b * CAP + idx];
    int dn = (b << BSH) | ((e.x >> 16) & 2047);
    int q = atomicAdd(&cursor[dn], 1);
    csr_pack[q] = make_int2(e.x & 0xFFFF, e.y);
}

// ---- xl = x@Wl + bl ; xr = x@Wr + br -> fp16 outputs (measured absmax 4.9e-4)
template<int K>
__global__ void linear_dual_k(const float* __restrict__ x,
                              const float* __restrict__ Wl, const float* __restrict__ bl,
                              const float* __restrict__ Wr, const float* __restrict__ br,
                              __half* __restrict__ xl, __half* __restrict__ xr) {
    const int NPW = 8;
    int wid = blockIdx.x * (blockDim.x >> 6) + (threadIdx.x >> 6);
    int d = threadIdx.x & 63;
    int n0 = wid * NPW;
    if (n0 >= N_NODES) return;
    float blv = bl[d], brv = br[d];
    float al[NPW], ar[NPW];
    #pragma unroll
    for (int i = 0; i < NPW; ++i) { al[i] = blv; ar[i] = brv; }
    const float4* xb = (const float4*)(x + (size_t)n0 * K);
    #pragma unroll 2
    for (int k4 = 0; k4 < K / 4; ++k4) {
        float4 xv[NPW];
        #pragma unroll
        for (int i = 0; i < NPW; ++i) xv[i] = xb[i * (K / 4) + k4];
        int kb = k4 * 4;
        float wl[4], wr[4];
        #pragma unroll
        for (int q = 0; q < 4; ++q) {
            wl[q] = Wl[(kb + q) * D_H + d];
            wr[q] = Wr[(kb + q) * D_H + d];
        }
        #pragma unroll
        for (int i = 0; i < NPW; ++i) {
            al[i] = fmaf(xv[i].x, wl[0], al[i]);
            al[i] = fmaf(xv[i].y, wl[1], al[i]);
            al[i] = fmaf(xv[i].z, wl[2], al[i]);
            al[i] = fmaf(xv[i].w, wl[3], al[i]);
            ar[i] = fmaf(xv[i].x, wr[0], ar[i]);
            ar[i] = fmaf(xv[i].y, wr[1], ar[i]);
            ar[i] = fmaf(xv[i].z, wr[2], ar[i]);
            ar[i] = fmaf(xv[i].w, wr[3], ar[i]);
        }
    }
    #pragma unroll
    for (int i = 0; i < NPW; ++i) {
        xl[(size_t)(n0 + i) * D_H + d] = __float2half(al[i]);
        xr[(size_t)(n0 + i) * D_H + d] = __float2half(ar[i]);
    }
}

// ---- fused GATv2 layer, 16-lane-group layout, 16 edges/iter, fp16 gathers.
// No running max (logits O(10), fp32 exp overflow at 88, shift-invariant).
__global__ void gat_fused(const int* __restrict__ row_start, const int2* __restrict__ csr_pack,
                          const __half* __restrict__ xl, const __half* __restrict__ xr,
                          const float* __restrict__ We, const float* __restrict__ att,
                          const float* __restrict__ b, float* __restrict__ out) {
    int node = blockIdx.x * (blockDim.x >> 6) + (threadIdx.x >> 6);
    if (node >= N_NODES) return;
    int lane = threadIdx.x & 63;
    int g = lane >> 4;
    int s = lane & 15;
    int fb = s * 4;
    float4 we4  = *(const float4*)(We + fb);
    float4 att4 = *(const float4*)(att + fb);
    float4 xr4  = ld_h4(xr + (size_t)node * D_H + fb);
    int j0 = row_start[node], j1 = row_start[node + 1];

    float S = 0.f;
    float4 acc = make_float4(0.f, 0.f, 0.f, 0.f);

    for (int base = j0; base < j1; base += 16) {
        int i0 = base + 4 * g;
        bool v0 = i0 < j1, v1 = i0 + 1 < j1, v2 = i0 + 2 < j1, v3 = i0 + 3 < j1;
        int c0 = v0 ? i0 : j0, c1 = v1 ? i0 + 1 : j0;
        int c2 = v2 ? i0 + 2 : j0, c3 = v3 ? i0 + 3 : j0;
        int2 p0 = csr_pack[c0], p1 = csr_pack[c1], p2 = csr_pack[c2], p3 = csr_pack[c3];
        float4 r0 = ld_h4(xl + (size_t)p0.x * D_H + fb);
        float4 r1 = ld_h4(xl + (size_t)p1.x * D_H + fb);
        float4 r2 = ld_h4(xl + (size_t)p2.x * D_H + fb);
        float4 r3 = ld_h4(xl + (size_t)p3.x * D_H + fb);
        float e0 = __int_as_float(p0.y), e1 = __int_as_float(p1.y);
        float e2 = __int_as_float(p2.y), e3 = __int_as_float(p3.y);

        float t0, t1, t2, t3;
        {
            float4 v;
            v.x = fmaf(e0, we4.x, r0.x + xr4.x); v.y = fmaf(e0, we4.y, r0.y + xr4.y);
            v.z = fmaf(e0, we4.z, r0.z + xr4.z); v.w = fmaf(e0, we4.w, r0.w + xr4.w);
            v.x = fmaxf(v.x, NEG_SLOPE * v.x); v.y = fmaxf(v.y, NEG_SLOPE * v.y);
            v.z = fmaxf(v.z, NEG_SLOPE * v.z); v.w = fmaxf(v.w, NEG_SLOPE * v.w);
            t0 = fmaf(v.w, att4.w, fmaf(v.z, att4.z, fmaf(v.y, att4.y, v.x * att4.x)));
            v.x = fmaf(e1, we4.x, r1.x + xr4.x); v.y = fmaf(e1, we4.y, r1.y + xr4.y);
            v.z = fmaf(e1, we4.z, r1.z + xr4.z); v.w = fmaf(e1, we4.w, r1.w + xr4.w);
            v.x = fmaxf(v.x, NEG_SLOPE * v.x); v.y = fmaxf(v.y, NEG_SLOPE * v.y);
            v.z = fmaxf(v.z, NEG_SLOPE * v.z); v.w = fmaxf(v.w, NEG_SLOPE * v.w);
            t1 = fmaf(v.w, att4.w, fmaf(v.z, att4.z, fmaf(v.y, att4.y, v.x * att4.x)));
            v.x = fmaf(e2, we4.x, r2.x + xr4.x); v.y = fmaf(e2, we4.y, r2.y + xr4.y);
            v.z = fmaf(e2, we4.z, r2.z + xr4.z); v.w = fmaf(e2, we4.w, r2.w + xr4.w);
            v.x = fmaxf(v.x, NEG_SLOPE * v.x); v.y = fmaxf(v.y, NEG_SLOPE * v.y);
            v.z = fmaxf(v.z, NEG_SLOPE * v.z); v.w = fmaxf(v.w, NEG_SLOPE * v.w);
            t2 = fmaf(v.w, att4.w, fmaf(v.z, att4.z, fmaf(v.y, att4.y, v.x * att4.x)));
            v.x = fmaf(e3, we4.x, r3.x + xr4.x); v.y = fmaf(e3, we4.y, r3.y + xr4.y);
            v.z = fmaf(e3, we4.z, r3.z + xr4.z); v.w = fmaf(e3, we4.w, r3.w + xr4.w);
            v.x = fmaxf(v.x, NEG_SLOPE * v.x); v.y = fmaxf(v.y, NEG_SLOPE * v.y);
            v.z = fmaxf(v.z, NEG_SLOPE * v.z); v.w = fmaxf(v.w, NEG_SLOPE * v.w);
            t3 = fmaf(v.w, att4.w, fmaf(v.z, att4.z, fmaf(v.y, att4.y, v.x * att4.x)));
        }
        #pragma unroll
        for (int off = 1; off <= 8; off <<= 1) {   // stays inside the 16-lane group
            t0 += __shfl_xor(t0, off);
            t1 += __shfl_xor(t1, off);
            t2 += __shfl_xor(t2, off);
            t3 += __shfl_xor(t3, off);
        }
        float z0 = v0 ? __expf(t0) : 0.f;
        float z1 = v1 ? __expf(t1) : 0.f;
        float z2 = v2 ? __expf(t2) : 0.f;
        float z3 = v3 ? __expf(t3) : 0.f;
        S += (z0 + z1) + (z2 + z3);
        acc.x = fmaf(z3, r3.x, fmaf(z2, r2.x, fmaf(z1, r1.x, fmaf(z0, r0.x, acc.x))));
        acc.y = fmaf(z3, r3.y, fmaf(z2, r2.y, fmaf(z1, r1.y, fmaf(z0, r0.y, acc.y))));
        acc.z = fmaf(z3, r3.z, fmaf(z2, r2.z, fmaf(z1, r1.z, fmaf(z0, r0.z, acc.z))));
        acc.w = fmaf(z3, r3.w, fmaf(z2, r2.w, fmaf(z1, r1.w, fmaf(z0, r0.w, acc.w))));
    }

    // plain sum-merge of the 4 groups (xor 16, then xor 32)
    #pragma unroll
    for (int off = 16; off <= 32; off <<= 1) {
        S     += __shfl_xor(S, off);
        acc.x += __shfl_xor(acc.x, off);
        acc.y += __shfl_xor(acc.y, off);
        acc.z += __shfl_xor(acc.z, off);
        acc.w += __shfl_xor(acc.w, off);
    }

    if (g == 0) {
        float4 b4 = *(const float4*)(b + fb);
        float inv = 1.f / (S + 1e-16f);
        float4 h;
        h.x = fmaf(acc.x, inv, b4.x);
        h.y = fmaf(acc.y, inv, b4.y);
        h.z = fmaf(acc.z, inv, b4.z);
        h.w = fmaf(acc.w, inv, b4.w);
        h.x = h.x > 0.f ? h.x : expm1f(h.x);
        h.y = h.y > 0.f ? h.y : expm1f(h.y);
        h.z = h.z > 0.f ? h.z : expm1f(h.z);
        h.w = h.w > 0.f ? h.w : expm1f(h.w);
        *(float4*)(out + (size_t)node * D_H + fb) = h;
    }
}

// ---- global mean pool (batch is sorted): register accumulate, flush on change
__global__ void pool(const float* __restrict__ h, const int* __restrict__ batch,
                     float* __restrict__ pooled, float* __restrict__ counts) {
    const int CHUNK = 128;
    int base = blockIdx.x * CHUNK;
    int d = threadIdx.x;  // blockDim = 64
    float accv = 0.f; int cur_g = -1; int cnt = 0;
    for (int i = 0; i < CHUNK; ++i) {
        int n = base + i;
        if (n >= N_NODES) break;
        int g = batch[n];
        if (g != cur_g) {
            if (cur_g >= 0) {
                atomicAdd(&pooled[cur_g * D_H + d], accv);
                if (d == 0) atomicAdd(&counts[cur_g], (float)cnt);
            }
            cur_g = g; accv = 0.f; cnt = 0;
        }
        accv += h[(size_t)n * D_H + d];
        cnt++;
    }
    if (cur_g >= 0) {
        atomicAdd(&pooled[cur_g * D_H + d], accv);
        if (d == 0) atomicAdd(&counts[cur_g], (float)cnt);
    }
}

__global__ void classify(const float* __restrict__ pooled, const float* __restrict__ counts,
                         const float* __restrict__ Wc, const float* __restrict__ bc,
                         float* __restrict__ out) {
    int tid = threadIdx.x;             // 640 threads
    int g = tid / N_CLS, c = tid % N_CLS;
    if (g >= N_GRAPHS) return;
    float inv = 1.0f / fmaxf(counts[g], 1.0f);
    float a = bc[c];
    for (int k = 0; k < D_H; ++k)
        a = fmaf(pooled[g * D_H + k] * inv, Wc[k * N_CLS + c], a);
    out[g * N_CLS + c] = a;
}

extern "C" void kernel_launch(void* const* d_in, const int* in_sizes, int n_in,
                              void* d_out, int out_size, void* d_ws, size_t ws_size,
                              hipStream_t stream) {
    const float* x     = (const float*)d_in[0];
    const int*   ei    = (const int*)d_in[1];
    const float* eattr = (const float*)d_in[2];
    const int*   batch = (const int*)d_in[3];
    const float *Wl1 = (const float*)d_in[4],  *bl1 = (const float*)d_in[5];
    const float *Wr1 = (const float*)d_in[6],  *br1 = (const float*)d_in[7];
    const float *We1 = (const float*)d_in[8],  *att1 = (const float*)d_in[9];
    const float *b1  = (const float*)d_in[10];
    const float *Wl2 = (const float*)d_in[11], *bl2 = (const float*)d_in[12];
    const float *Wr2 = (const float*)d_in[13], *br2 = (const float*)d_in[14];
    const float *We2 = (const float*)d_in[15], *att2 = (const float*)d_in[16];
    const float *b2  = (const float*)d_in[17];
    const float *Wc  = (const float*)d_in[18], *bc = (const float*)d_in[19];
    float* out = (float*)d_out;

    const int* src = ei;
    const int* dst = ei + N_EDGES;

    // workspace layout. stg (int2, 15.36 MB) is dead after scatter; xl/xr (fp16,
    // 6.4 MB each) + h (fp32, 12.8 MB) = 25.6 MB alias its region. csr_pack kept
    // at the old 30.72 MB offset so it stays clear of xl/xr/h.
    char* base = (char*)d_ws;
    int2*  stg     = (int2*)base;                       // NB*CAP*8B = 15.36 MB
    __half* xl     = (__half*)base;                     // N*64 fp16 (6.4 MB)
    __half* xr     = xl + (size_t)N_NODES * D_H;        // N*64 fp16
    float* h       = (float*)(xr + (size_t)N_NODES * D_H); // N*64 fp32 (12.8 MB)
    int2*  csr_pack = (int2*)(base + (size_t)NB * CAP * 16); // E2 (8B) = 13.2 MB
    int*   row_start = (int*)(csr_pack + E2);           // N+1
    int*   cnt     = row_start + N_NODES + 1;           // N
    float* esum    = (float*)(cnt + N_NODES);           // 32 lines (32*PAD floats)
    int*   bcursor = (int*)(esum + 32 * PAD);           // NB lines (NB*PAD ints)
    int*   cursor  = bcursor + NB * PAD;                // N
    int*   partial = cursor + N_NODES;                  // NBLK
    float* pooled  = (float*)(partial + NBLK);          // 64*64
    float* counts  = pooled + N_GRAPHS * D_H;           // 64

    const int WPB = 4;  // waves per block at 256 threads
    int node_wave_blocks = (N_NODES + WPB - 1) / WPB;
    int lin_blocks = (N_NODES / 8 + WPB - 1) / WPB;

    hipMemsetAsync(cnt, 0, (N_NODES + 32 * PAD + NB * PAD) * sizeof(int), stream);
    hipMemsetAsync(pooled, 0, (N_GRAPHS * D_H + N_GRAPHS) * sizeof(float), stream);

    // ---- CSR build: stage -> LDS hist -> scan -> scatter ----
    bucket_stage<<<(N_EDGES / EPT + 255) / 256, 256, 0, stream>>>(
        src, dst, eattr, esum, bcursor, stg);
    hist_bucket<<<NB * HBB, 256, 0, stream>>>(stg, bcursor, cnt);
    scan_block<<<NBLK, SCAN_BS, 0, stream>>>(cnt, row_start, partial);
    add_offsets<<<NBLK, SCAN_BS, 0, stream>>>(row_start, partial, cursor, esum, csr_pack);
    scatter_bucketed<<<8 * ((NB + 7) / 8) * CHUNKS, 256, 0, stream>>>(
        stg, bcursor, cursor, csr_pack);

    // ---------------- layer 1 ----------------
    linear_dual_k<D_IN><<<lin_blocks, 256, 0, stream>>>(x, Wl1, bl1, Wr1, br1, xl, xr);
    gat_fused<<<node_wave_blocks, 256, 0, stream>>>(row_start, csr_pack, xl, xr, We1, att1, b1, h);

    // ---------------- layer 2 ----------------
    linear_dual_k<D_H><<<lin_blocks, 256, 0, stream>>>(h, Wl2, bl2, Wr2, br2, xl, xr);
    gat_fused<<<node_wave_blocks, 256, 0, stream>>>(row_start, csr_pack, xl, xr, We2, att2, b2, h);

    // ---------------- pool + classify ----------------
    pool<<<(N_NODES + 127) / 128, 64, 0, stream>>>(h, batch, pooled, counts);
    classify<<<1, 640, 0, stream>>>(pooled, counts, Wc, bc, out);
}

// Round 2
// 456.142 us; speedup vs baseline: 1.2581x; 1.0885x over previous
//
#include <hip/hip_runtime.h>
#include <hip/hip_fp16.h>
#include <math.h>

#define N_NODES 50000
#define N_EDGES 1600000
#define D_IN 128
#define D_H 64
#define N_CLS 10
#define N_GRAPHS 64
#define NEG_SLOPE 0.2f
#define E2 (N_EDGES + N_NODES)   // edges + self loops
#define SCAN_BS 256
#define NBLK ((N_NODES + SCAN_BS - 1) / SCAN_BS)   // 196 <= 256

// bucketed scatter params
#define NB 25                 // buckets: dst >> 11 (50000/2048 -> 0..24)
#define BSH 11
#define CAP 76800             // per-bucket staging capacity (>40 sigma over E/NB)
#define CHUNKS (CAP / 256)    // 300 blocks per bucket in pass B
#define HBB 8                 // hist blocks per bucket
#define EPT 8                 // edges/thread in bucket_stage
#define PAD 32                // 128B stride: one cache line per contended counter

__device__ inline float wave_reduce_sum(float v) {
    for (int off = 32; off; off >>= 1) v += __shfl_xor(v, off);
    return v;
}

// one 8B load -> 4 floats from fp16 row chunk
__device__ inline float4 ld_h4(const __half* p) {
    int2 raw = *(const int2*)p;
    __half2 a = *(__half2*)&raw.x;
    __half2 b = *(__half2*)&raw.y;
    return make_float4(__low2float(a), __high2float(a), __low2float(b), __high2float(b));
}

// ===== pass A: bucket-stage edges + eattr sum.
// r0 fix (verified): contended-line atomics were the serializer. esum spread
// over 32 lines, bcursor one line per bucket, EPT=8, int2 staging.
__global__ void bucket_stage(const int* __restrict__ src, const int* __restrict__ dst,
                             const float* __restrict__ eattr,
                             float* esum, int* bcursor,
                             int2* __restrict__ stg) {
    __shared__ int bcnt[4][32];
    __shared__ int woff[4][32];
    __shared__ float esh[4];
    int t = threadIdx.x;
    int wave = t >> 6;
    if (t < 128) bcnt[t >> 5][t & 31] = 0;
    __syncthreads();
    int e0 = (blockIdx.x * blockDim.x + t) * EPT;   // N_EDGES % EPT == 0
    int ss[EPT], tt[EPT], aa[EPT], r[EPT], b[EPT];
    float v = 0.f;
    bool valid = e0 < N_EDGES;
    if (valid) {
        #pragma unroll
        for (int q = 0; q < EPT / 4; ++q) {
            int4 s4 = *(const int4*)(src + e0 + 4 * q);
            int4 t4 = *(const int4*)(dst + e0 + 4 * q);
            float4 a4 = *(const float4*)(eattr + e0 + 4 * q);
            ss[4*q] = s4.x; ss[4*q+1] = s4.y; ss[4*q+2] = s4.z; ss[4*q+3] = s4.w;
            tt[4*q] = t4.x; tt[4*q+1] = t4.y; tt[4*q+2] = t4.z; tt[4*q+3] = t4.w;
            aa[4*q]   = __float_as_int(a4.x); aa[4*q+1] = __float_as_int(a4.y);
            aa[4*q+2] = __float_as_int(a4.z); aa[4*q+3] = __float_as_int(a4.w);
            v += (a4.x + a4.y) + (a4.z + a4.w);
        }
        #pragma unroll
        for (int i = 0; i < EPT; ++i) {
            b[i] = tt[i] >> BSH;
            r[i] = atomicAdd(&bcnt[wave][b[i]], 1);
        }
    }
    v = wave_reduce_sum(v);
    if ((t & 63) == 0) esh[wave] = v;
    __syncthreads();
    if (t < NB) {
        int c0 = bcnt[0][t], c1 = bcnt[1][t], c2 = bcnt[2][t], c3 = bcnt[3][t];
        int tot = c0 + c1 + c2 + c3;
        int base = tot ? atomicAdd(&bcursor[t * PAD], tot) : 0;
        woff[0][t] = base;
        woff[1][t] = base + c0;
        woff[2][t] = base + c0 + c1;
        woff[3][t] = base + c0 + c1 + c2;
    }
    if (t == 0) {
        float tot = (esh[0] + esh[1]) + (esh[2] + esh[3]);
        atomicAdd(&esum[(blockIdx.x & 31) * PAD], tot);   // 32 distinct lines
    }
    __syncthreads();
    if (valid) {
        #pragma unroll
        for (int i = 0; i < EPT; ++i) {
            int p = b[i] * CAP + woff[wave][b[i]] + r[i];
            stg[p] = make_int2((ss[i] & 0xFFFF) | ((tt[i] & 2047) << 16), aa[i]);
        }
    }
}

// ===== pass A2: per-node histogram from staged dst-low bits, LDS-resident window
__global__ void hist_bucket(const int2* __restrict__ stg, const int* __restrict__ bcursor,
                            int* cnt) {
    __shared__ int hist[2048];
    int b = blockIdx.x / HBB;
    int j = blockIdx.x % HBB;
    for (int i = threadIdx.x; i < 2048; i += 256) hist[i] = 0;
    __syncthreads();
    int n = bcursor[b * PAD];
    const int2* sd = stg + (size_t)b * CAP;
    int per = (n + HBB - 1) / HBB;
    int start = j * per;
    int end = min(start + per, n);
    for (int idx = start + threadIdx.x; idx < end; idx += 256)
        atomicAdd(&hist[(sd[idx].x >> 16) & 2047], 1);
    __syncthreads();
    int nb = b << BSH;
    for (int i = threadIdx.x; i < 2048; i += 256) {
        int c = hist[i];
        if (c) atomicAdd(&cnt[nb + i], c);
    }
}

// ---- block-local exclusive scan; +1 per node folds in the self-loop slot ----
__global__ void scan_block(const int* __restrict__ cnt, int* __restrict__ row_start,
                           int* __restrict__ partial) {
    __shared__ int sd[SCAN_BS];
    int i = blockIdx.x * SCAN_BS + threadIdx.x;
    int v = (i < N_NODES) ? (cnt[i] + 1) : 0;   // +1 = self loop
    sd[threadIdx.x] = v;
    __syncthreads();
    for (int off = 1; off < SCAN_BS; off <<= 1) {
        int t = (threadIdx.x >= off) ? sd[threadIdx.x - off] : 0;
        __syncthreads();
        sd[threadIdx.x] += t;
        __syncthreads();
    }
    if (i < N_NODES) row_start[i] = sd[threadIdx.x] - v;
    if (threadIdx.x == SCAN_BS - 1) partial[blockIdx.x] = sd[threadIdx.x];
}
// finalize row_start (redundant LDS scan of partials replaces a launch),
// write self-loop CSR entry, seed cursor
__global__ void add_offsets(int* __restrict__ row_start, const int* __restrict__ partial,
                            int* __restrict__ cursor, const float* __restrict__ esum,
                            int2* __restrict__ csr_pack) {
    __shared__ int sp[SCAN_BS];
    int pv = (threadIdx.x < NBLK) ? partial[threadIdx.x] : 0;
    sp[threadIdx.x] = pv;
    __syncthreads();
    for (int off = 1; off < SCAN_BS; off <<= 1) {
        int t = (threadIdx.x >= off) ? sp[threadIdx.x - off] : 0;
        __syncthreads();
        sp[threadIdx.x] += t;
        __syncthreads();
    }
    float es = 0.f;
    #pragma unroll
    for (int jj = 0; jj < 32; ++jj) es += esum[jj * PAD];
    int base = (blockIdx.x == 0) ? 0 : sp[blockIdx.x - 1];
    int i = blockIdx.x * SCAN_BS + threadIdx.x;
    if (i < N_NODES) {
        int r = row_start[i] + base;
        row_start[i] = r;
        csr_pack[r] = make_int2(i, __float_as_int(es * (1.0f / N_EDGES)));
        cursor[i] = r + 1;
    }
    if (i == 0) row_start[N_NODES] = E2;
}

// ===== pass B: scatter within buckets (L2-confined windows, XCD swizzle)
__global__ void scatter_bucketed(const int2* __restrict__ stg,
                                 const int* __restrict__ bcursor, int* cursor,
                                 int2* __restrict__ csr_pack) {
    int g = blockIdx.x;
    int xcd = g & 7;
    int k = g >> 3;
    int b = xcd + 8 * (k / CHUNKS);
    if (b >= NB) return;
    int j = k % CHUNKS;
    int n = bcursor[b * PAD];
    int idx = j * 256 + threadIdx.x;
    if (idx >= n) return;
    int2 e = stg[(size_t)b * CAP + idx];
    int dn = (b << BSH) | ((e.x >> 16) & 2047);
    int q = atomicAdd(&cursor[dn], 1);
    csr_pack[q] = make_int2(e.x & 0xFFFF, e.y);
}

// ---- xl = x@Wl + bl ; xr = x@Wr + br -> fp16 outputs.
// r1 rewrite: old version issued wave-BROADCAST global loads for x (lane-
// invariant address, 16B useful per VMEM instr, ~200-900cy latency each) ->
// VALUBusy 23%, dur 78us vs 10us fp32-FMA roofline. Now: stage a 64-node
// x-tile in LDS via fully-coalesced float4 loads (4KB/instr), compute reads
// LDS broadcast (conflict-free). 16 nodes/wave halves L2 weight reloads.
template<int K>
__global__ __launch_bounds__(256) void linear_dual_k(
                              const float* __restrict__ x,
                              const float* __restrict__ Wl, const float* __restrict__ bl,
                              const float* __restrict__ Wr, const float* __restrict__ br,
                              __half* __restrict__ xl, __half* __restrict__ xr) {
    const int TN = 64;            // nodes per block
    const int NPW = TN / 4;       // 16 nodes per wave
    __shared__ float xs[TN * K];  // 32KB (K=128) / 16KB (K=64)
    int t = threadIdx.x;
    int nb = blockIdx.x * TN;
    int rem = N_NODES - nb;
    int tot4 = (rem >= TN ? TN : rem) * (K / 4);
    const float4* xg = (const float4*)(x + (size_t)nb * K);
    float4* xs4 = (float4*)xs;
    for (int i = t; i < tot4; i += 256) xs4[i] = xg[i];
    __syncthreads();
    int wave = t >> 6, d = t & 63;
    int n0 = wave * NPW;
    float blv = bl[d], brv = br[d];
    float al[NPW], ar[NPW];
    #pragma unroll
    for (int i = 0; i < NPW; ++i) { al[i] = blv; ar[i] = brv; }
    #pragma unroll 2
    for (int k4 = 0; k4 < K / 4; ++k4) {
        int kb = k4 * 4;
        float wl[4], wr[4];
        #pragma unroll
        for (int q = 0; q < 4; ++q) {
            wl[q] = Wl[(kb + q) * D_H + d];
            wr[q] = Wr[(kb + q) * D_H + d];
        }
        #pragma unroll
        for (int i = 0; i < NPW; ++i) {
            float4 xv = *(const float4*)&xs[(n0 + i) * K + kb];  // LDS broadcast
            al[i] = fmaf(xv.x, wl[0], al[i]);
            al[i] = fmaf(xv.y, wl[1], al[i]);
            al[i] = fmaf(xv.z, wl[2], al[i]);
            al[i] = fmaf(xv.w, wl[3], al[i]);
            ar[i] = fmaf(xv.x, wr[0], ar[i]);
            ar[i] = fmaf(xv.y, wr[1], ar[i]);
            ar[i] = fmaf(xv.z, wr[2], ar[i]);
            ar[i] = fmaf(xv.w, wr[3], ar[i]);
        }
    }
    #pragma unroll
    for (int i = 0; i < NPW; ++i) {
        int g = nb + n0 + i;
        if (g < N_NODES) {
            xl[(size_t)g * D_H + d] = __float2half(al[i]);
            xr[(size_t)g * D_H + d] = __float2half(ar[i]);
        }
    }
}

// ---- fused GATv2 layer, 16-lane-group layout, 16 edges/iter, fp16 gathers.
// No running max (logits O(10), fp32 exp overflow at 88, shift-invariant).
__global__ void gat_fused(const int* __restrict__ row_start, const int2* __restrict__ csr_pack,
                          const __half* __restrict__ xl, const __half* __restrict__ xr,
                          const float* __restrict__ We, const float* __restrict__ att,
                          const float* __restrict__ b, float* __restrict__ out) {
    int node = blockIdx.x * (blockDim.x >> 6) + (threadIdx.x >> 6);
    if (node >= N_NODES) return;
    int lane = threadIdx.x & 63;
    int g = lane >> 4;
    int s = lane & 15;
    int fb = s * 4;
    float4 we4  = *(const float4*)(We + fb);
    float4 att4 = *(const float4*)(att + fb);
    float4 xr4  = ld_h4(xr + (size_t)node * D_H + fb);
    int j0 = row_start[node], j1 = row_start[node + 1];

    float S = 0.f;
    float4 acc = make_float4(0.f, 0.f, 0.f, 0.f);

    for (int base = j0; base < j1; base += 16) {
        int i0 = base + 4 * g;
        bool v0 = i0 < j1, v1 = i0 + 1 < j1, v2 = i0 + 2 < j1, v3 = i0 + 3 < j1;
        int c0 = v0 ? i0 : j0, c1 = v1 ? i0 + 1 : j0;
        int c2 = v2 ? i0 + 2 : j0, c3 = v3 ? i0 + 3 : j0;
        int2 p0 = csr_pack[c0], p1 = csr_pack[c1], p2 = csr_pack[c2], p3 = csr_pack[c3];
        float4 r0 = ld_h4(xl + (size_t)p0.x * D_H + fb);
        float4 r1 = ld_h4(xl + (size_t)p1.x * D_H + fb);
        float4 r2 = ld_h4(xl + (size_t)p2.x * D_H + fb);
        float4 r3 = ld_h4(xl + (size_t)p3.x * D_H + fb);
        float e0 = __int_as_float(p0.y), e1 = __int_as_float(p1.y);
        float e2 = __int_as_float(p2.y), e3 = __int_as_float(p3.y);

        float t0, t1, t2, t3;
        {
            float4 v;
            v.x = fmaf(e0, we4.x, r0.x + xr4.x); v.y = fmaf(e0, we4.y, r0.y + xr4.y);
            v.z = fmaf(e0, we4.z, r0.z + xr4.z); v.w = fmaf(e0, we4.w, r0.w + xr4.w);
            v.x = fmaxf(v.x, NEG_SLOPE * v.x); v.y = fmaxf(v.y, NEG_SLOPE * v.y);
            v.z = fmaxf(v.z, NEG_SLOPE * v.z); v.w = fmaxf(v.w, NEG_SLOPE * v.w);
            t0 = fmaf(v.w, att4.w, fmaf(v.z, att4.z, fmaf(v.y, att4.y, v.x * att4.x)));
            v.x = fmaf(e1, we4.x, r1.x + xr4.x); v.y = fmaf(e1, we4.y, r1.y + xr4.y);
            v.z = fmaf(e1, we4.z, r1.z + xr4.z); v.w = fmaf(e1, we4.w, r1.w + xr4.w);
            v.x = fmaxf(v.x, NEG_SLOPE * v.x); v.y = fmaxf(v.y, NEG_SLOPE * v.y);
            v.z = fmaxf(v.z, NEG_SLOPE * v.z); v.w = fmaxf(v.w, NEG_SLOPE * v.w);
            t1 = fmaf(v.w, att4.w, fmaf(v.z, att4.z, fmaf(v.y, att4.y, v.x * att4.x)));
            v.x = fmaf(e2, we4.x, r2.x + xr4.x); v.y = fmaf(e2, we4.y, r2.y + xr4.y);
            v.z = fmaf(e2, we4.z, r2.z + xr4.z); v.w = fmaf(e2, we4.w, r2.w + xr4.w);
            v.x = fmaxf(v.x, NEG_SLOPE * v.x); v.y = fmaxf(v.y, NEG_SLOPE * v.y);
            v.z = fmaxf(v.z, NEG_SLOPE * v.z); v.w = fmaxf(v.w, NEG_SLOPE * v.w);
            t2 = fmaf(v.w, att4.w, fmaf(v.z, att4.z, fmaf(v.y, att4.y, v.x * att4.x)));
            v.x = fmaf(e3, we4.x, r3.x + xr4.x); v.y = fmaf(e3, we4.y, r3.y + xr4.y);
            v.z = fmaf(e3, we4.z, r3.z + xr4.z); v.w = fmaf(e3, we4.w, r3.w + xr4.w);
            v.x = fmaxf(v.x, NEG_SLOPE * v.x); v.y = fmaxf(v.y, NEG_SLOPE * v.y);
            v.z = fmaxf(v.z, NEG_SLOPE * v.z); v.w = fmaxf(v.w, NEG_SLOPE * v.w);
            t3 = fmaf(v.w, att4.w, fmaf(v.z, att4.z, fmaf(v.y, att4.y, v.x * att4.x)));
        }
        #pragma unroll
        for (int off = 1; off <= 8; off <<= 1) {   // stays inside the 16-lane group
            t0 += __shfl_xor(t0, off);
            t1 += __shfl_xor(t1, off);
            t2 += __shfl_xor(t2, off);
            t3 += __shfl_xor(t3, off);
        }
        float z0 = v0 ? __expf(t0) : 0.f;
        float z1 = v1 ? __expf(t1) : 0.f;
        float z2 = v2 ? __expf(t2) : 0.f;
        float z3 = v3 ? __expf(t3) : 0.f;
        S += (z0 + z1) + (z2 + z3);
        acc.x = fmaf(z3, r3.x, fmaf(z2, r2.x, fmaf(z1, r1.x, fmaf(z0, r0.x, acc.x))));
        acc.y = fmaf(z3, r3.y, fmaf(z2, r2.y, fmaf(z1, r1.y, fmaf(z0, r0.y, acc.y))));
        acc.z = fmaf(z3, r3.z, fmaf(z2, r2.z, fmaf(z1, r1.z, fmaf(z0, r0.z, acc.z))));
        acc.w = fmaf(z3, r3.w, fmaf(z2, r2.w, fmaf(z1, r1.w, fmaf(z0, r0.w, acc.w))));
    }

    // plain sum-merge of the 4 groups (xor 16, then xor 32)
    #pragma unroll
    for (int off = 16; off <= 32; off <<= 1) {
        S     += __shfl_xor(S, off);
        acc.x += __shfl_xor(acc.x, off);
        acc.y += __shfl_xor(acc.y, off);
        acc.z += __shfl_xor(acc.z, off);
        acc.w += __shfl_xor(acc.w, off);
    }

    if (g == 0) {
        float4 b4 = *(const float4*)(b + fb);
        float inv = 1.f / (S + 1e-16f);
        float4 h;
        h.x = fmaf(acc.x, inv, b4.x);
        h.y = fmaf(acc.y, inv, b4.y);
        h.z = fmaf(acc.z, inv, b4.z);
        h.w = fmaf(acc.w, inv, b4.w);
        h.x = h.x > 0.f ? h.x : expm1f(h.x);
        h.y = h.y > 0.f ? h.y : expm1f(h.y);
        h.z = h.z > 0.f ? h.z : expm1f(h.z);
        h.w = h.w > 0.f ? h.w : expm1f(h.w);
        *(float4*)(out + (size_t)node * D_H + fb) = h;
    }
}

// ---- global mean pool (batch is sorted): register accumulate, flush on change
__global__ void pool(const float* __restrict__ h, const int* __restrict__ batch,
                     float* __restrict__ pooled, float* __restrict__ counts) {
    const int CHUNK = 128;
    int base = blockIdx.x * CHUNK;
    int d = threadIdx.x;  // blockDim = 64
    float accv = 0.f; int cur_g = -1; int cnt = 0;
    for (int i = 0; i < CHUNK; ++i) {
        int n = base + i;
        if (n >= N_NODES) break;
        int g = batch[n];
        if (g != cur_g) {
            if (cur_g >= 0) {
                atomicAdd(&pooled[cur_g * D_H + d], accv);
                if (d == 0) atomicAdd(&counts[cur_g], (float)cnt);
            }
            cur_g = g; accv = 0.f; cnt = 0;
        }
        accv += h[(size_t)n * D_H + d];
        cnt++;
    }
    if (cur_g >= 0) {
        atomicAdd(&pooled[cur_g * D_H + d], accv);
        if (d == 0) atomicAdd(&counts[cur_g], (float)cnt);
    }
}

__global__ void classify(const float* __restrict__ pooled, const float* __restrict__ counts,
                         const float* __restrict__ Wc, const float* __restrict__ bc,
                         float* __restrict__ out) {
    int tid = threadIdx.x;             // 640 threads
    int g = tid / N_CLS, c = tid % N_CLS;
    if (g >= N_GRAPHS) return;
    float inv = 1.0f / fmaxf(counts[g], 1.0f);
    float a = bc[c];
    for (int k = 0; k < D_H; ++k)
        a = fmaf(pooled[g * D_H + k] * inv, Wc[k * N_CLS + c], a);
    out[g * N_CLS + c] = a;
}

extern "C" void kernel_launch(void* const* d_in, const int* in_sizes, int n_in,
                              void* d_out, int out_size, void* d_ws, size_t ws_size,
                              hipStream_t stream) {
    const float* x     = (const float*)d_in[0];
    const int*   ei    = (const int*)d_in[1];
    const float* eattr = (const float*)d_in[2];
    const int*   batch = (const int*)d_in[3];
    const float *Wl1 = (const float*)d_in[4],  *bl1 = (const float*)d_in[5];
    const float *Wr1 = (const float*)d_in[6],  *br1 = (const float*)d_in[7];
    const float *We1 = (const float*)d_in[8],  *att1 = (const float*)d_in[9];
    const float *b1  = (const float*)d_in[10];
    const float *Wl2 = (const float*)d_in[11], *bl2 = (const float*)d_in[12];
    const float *Wr2 = (const float*)d_in[13], *br2 = (const float*)d_in[14];
    const float *We2 = (const float*)d_in[15], *att2 = (const float*)d_in[16];
    const float *b2  = (const float*)d_in[17];
    const float *Wc  = (const float*)d_in[18], *bc = (const float*)d_in[19];
    float* out = (float*)d_out;

    const int* src = ei;
    const int* dst = ei + N_EDGES;

    // workspace layout. stg (int2, 15.36 MB) is dead after scatter; xl/xr (fp16,
    // 6.4 MB each) + h (fp32, 12.8 MB) = 25.6 MB alias its region. csr_pack kept
    // at the old 30.72 MB offset so it stays clear of xl/xr/h.
    char* base = (char*)d_ws;
    int2*  stg     = (int2*)base;                       // NB*CAP*8B = 15.36 MB
    __half* xl     = (__half*)base;                     // N*64 fp16 (6.4 MB)
    __half* xr     = xl + (size_t)N_NODES * D_H;        // N*64 fp16
    float* h       = (float*)(xr + (size_t)N_NODES * D_H); // N*64 fp32 (12.8 MB)
    int2*  csr_pack = (int2*)(base + (size_t)NB * CAP * 16); // E2 (8B) = 13.2 MB
    int*   row_start = (int*)(csr_pack + E2);           // N+1
    int*   cnt     = row_start + N_NODES + 1;           // N
    float* esum    = (float*)(cnt + N_NODES);           // 32 lines (32*PAD floats)
    int*   bcursor = (int*)(esum + 32 * PAD);           // NB lines (NB*PAD ints)
    int*   cursor  = bcursor + NB * PAD;                // N
    int*   partial = cursor + N_NODES;                  // NBLK
    float* pooled  = (float*)(partial + NBLK);          // 64*64
    float* counts  = pooled + N_GRAPHS * D_H;           // 64

    const int WPB = 4;  // waves per block at 256 threads
    int node_wave_blocks = (N_NODES + WPB - 1) / WPB;
    int lin_blocks = (N_NODES + 63) / 64;               // 64 nodes per block

    hipMemsetAsync(cnt, 0, (N_NODES + 32 * PAD + NB * PAD) * sizeof(int), stream);
    hipMemsetAsync(pooled, 0, (N_GRAPHS * D_H + N_GRAPHS) * sizeof(float), stream);

    // ---- CSR build: stage -> LDS hist -> scan -> scatter ----
    bucket_stage<<<(N_EDGES / EPT + 255) / 256, 256, 0, stream>>>(
        src, dst, eattr, esum, bcursor, stg);
    hist_bucket<<<NB * HBB, 256, 0, stream>>>(stg, bcursor, cnt);
    scan_block<<<NBLK, SCAN_BS, 0, stream>>>(cnt, row_start, partial);
    add_offsets<<<NBLK, SCAN_BS, 0, stream>>>(row_start, partial, cursor, esum, csr_pack);
    scatter_bucketed<<<8 * ((NB + 7) / 8) * CHUNKS, 256, 0, stream>>>(
        stg, bcursor, cursor, csr_pack);

    // ---------------- layer 1 ----------------
    linear_dual_k<D_IN><<<lin_blocks, 256, 0, stream>>>(x, Wl1, bl1, Wr1, br1, xl, xr);
    gat_fused<<<node_wave_blocks, 256, 0, stream>>>(row_start, csr_pack, xl, xr, We1, att1, b1, h);

    // ---------------- layer 2 ----------------
    linear_dual_k<D_H><<<lin_blocks, 256, 0, stream>>>(h, Wl2, bl2, Wr2, br2, xl, xr);
    gat_fused<<<node_wave_blocks, 256, 0, stream>>>(row_start, csr_pack, xl, xr, We2, att2, b2, h);

    // ---------------- pool + classify ----------------
    pool<<<(N_NODES + 127) / 128, 64, 0, stream>>>(h, batch, pooled, counts);
    classify<<<1, 640, 0, stream>>>(pooled, counts, Wc, bc, out);
}

// Round 3
// 454.249 us; speedup vs baseline: 1.2633x; 1.0042x over previous
//
#include <hip/hip_runtime.h>
#include <hip/hip_fp16.h>
#include <math.h>

#define N_NODES 50000
#define N_EDGES 1600000
#define D_IN 128
#define D_H 64
#define N_CLS 10
#define N_GRAPHS 64
#define NEG_SLOPE 0.2f
#define E2 (N_EDGES + N_NODES)   // edges + self loops
#define SCAN_BS 256
#define NBLK ((N_NODES + SCAN_BS - 1) / SCAN_BS)   // 196 <= 256

// bucketed scatter params
#define NB 25                 // buckets: dst >> 11 (50000/2048 -> 0..24)
#define BSH 11
#define CAP 76800             // per-bucket staging capacity (>40 sigma over E/NB)
#define HBB 8                 // hist blocks per bucket
#define EPT 8                 // edges/thread in bucket_stage
#define PAD 32                // 128B stride: one cache line per contended counter
#define SLICES 16             // node-slices per bucket in scatter_slice
#define SLICE_W (2048 / SLICES)   // 128 nodes per slice

__device__ inline float wave_reduce_sum(float v) {
    for (int off = 32; off; off >>= 1) v += __shfl_xor(v, off);
    return v;
}

// one 8B load -> 4 floats from fp16 row chunk
__device__ inline float4 ld_h4(const __half* p) {
    int2 raw = *(const int2*)p;
    __half2 a = *(__half2*)&raw.x;
    __half2 b = *(__half2*)&raw.y;
    return make_float4(__low2float(a), __high2float(a), __low2float(b), __high2float(b));
}

// ===== pass A: bucket-stage edges + eattr sum.
// r0 fix (verified): contended-line atomics were the serializer. esum spread
// over 32 lines, bcursor one line per bucket, EPT=8, int2 staging.
__global__ void bucket_stage(const int* __restrict__ src, const int* __restrict__ dst,
                             const float* __restrict__ eattr,
                             float* esum, int* bcursor,
                             int2* __restrict__ stg) {
    __shared__ int bcnt[4][32];
    __shared__ int woff[4][32];
    __shared__ float esh[4];
    int t = threadIdx.x;
    int wave = t >> 6;
    if (t < 128) bcnt[t >> 5][t & 31] = 0;
    __syncthreads();
    int e0 = (blockIdx.x * blockDim.x + t) * EPT;   // N_EDGES % EPT == 0
    int ss[EPT], tt[EPT], aa[EPT], r[EPT], b[EPT];
    float v = 0.f;
    bool valid = e0 < N_EDGES;
    if (valid) {
        #pragma unroll
        for (int q = 0; q < EPT / 4; ++q) {
            int4 s4 = *(const int4*)(src + e0 + 4 * q);
            int4 t4 = *(const int4*)(dst + e0 + 4 * q);
            float4 a4 = *(const float4*)(eattr + e0 + 4 * q);
            ss[4*q] = s4.x; ss[4*q+1] = s4.y; ss[4*q+2] = s4.z; ss[4*q+3] = s4.w;
            tt[4*q] = t4.x; tt[4*q+1] = t4.y; tt[4*q+2] = t4.z; tt[4*q+3] = t4.w;
            aa[4*q]   = __float_as_int(a4.x); aa[4*q+1] = __float_as_int(a4.y);
            aa[4*q+2] = __float_as_int(a4.z); aa[4*q+3] = __float_as_int(a4.w);
            v += (a4.x + a4.y) + (a4.z + a4.w);
        }
        #pragma unroll
        for (int i = 0; i < EPT; ++i) {
            b[i] = tt[i] >> BSH;
            r[i] = atomicAdd(&bcnt[wave][b[i]], 1);
        }
    }
    v = wave_reduce_sum(v);
    if ((t & 63) == 0) esh[wave] = v;
    __syncthreads();
    if (t < NB) {
        int c0 = bcnt[0][t], c1 = bcnt[1][t], c2 = bcnt[2][t], c3 = bcnt[3][t];
        int tot = c0 + c1 + c2 + c3;
        int base = tot ? atomicAdd(&bcursor[t * PAD], tot) : 0;
        woff[0][t] = base;
        woff[1][t] = base + c0;
        woff[2][t] = base + c0 + c1;
        woff[3][t] = base + c0 + c1 + c2;
    }
    if (t == 0) {
        float tot = (esh[0] + esh[1]) + (esh[2] + esh[3]);
        atomicAdd(&esum[(blockIdx.x & 31) * PAD], tot);   // 32 distinct lines
    }
    __syncthreads();
    if (valid) {
        #pragma unroll
        for (int i = 0; i < EPT; ++i) {
            int p = b[i] * CAP + woff[wave][b[i]] + r[i];
            stg[p] = make_int2((ss[i] & 0xFFFF) | ((tt[i] & 2047) << 16), aa[i]);
        }
    }
}

// ===== pass A2: per-node histogram from staged dst-low bits, LDS-resident window
__global__ void hist_bucket(const int2* __restrict__ stg, const int* __restrict__ bcursor,
                            int* cnt) {
    __shared__ int hist[2048];
    int b = blockIdx.x / HBB;
    int j = blockIdx.x % HBB;
    for (int i = threadIdx.x; i < 2048; i += 256) hist[i] = 0;
    __syncthreads();
    int n = bcursor[b * PAD];
    const int2* sd = stg + (size_t)b * CAP;
    int per = (n + HBB - 1) / HBB;
    int start = j * per;
    int end = min(start + per, n);
    for (int idx = start + threadIdx.x; idx < end; idx += 256)
        atomicAdd(&hist[(sd[idx].x >> 16) & 2047], 1);
    __syncthreads();
    int nb = b << BSH;
    for (int i = threadIdx.x; i < 2048; i += 256) {
        int c = hist[i];
        if (c) atomicAdd(&cnt[nb + i], c);
    }
}

// ---- block-local exclusive scan; +1 per node folds in the self-loop slot ----
__global__ void scan_block(const int* __restrict__ cnt, int* __restrict__ row_start,
                           int* __restrict__ partial) {
    __shared__ int sd[SCAN_BS];
    int i = blockIdx.x * SCAN_BS + threadIdx.x;
    int v = (i < N_NODES) ? (cnt[i] + 1) : 0;   // +1 = self loop
    sd[threadIdx.x] = v;
    __syncthreads();
    for (int off = 1; off < SCAN_BS; off <<= 1) {
        int t = (threadIdx.x >= off) ? sd[threadIdx.x - off] : 0;
        __syncthreads();
        sd[threadIdx.x] += t;
        __syncthreads();
    }
    if (i < N_NODES) row_start[i] = sd[threadIdx.x] - v;
    if (threadIdx.x == SCAN_BS - 1) partial[blockIdx.x] = sd[threadIdx.x];
}
// finalize row_start (redundant LDS scan of partials replaces a launch),
// write self-loop CSR entry, seed cursor
__global__ void add_offsets(int* __restrict__ row_start, const int* __restrict__ partial,
                            int* __restrict__ cursor, const float* __restrict__ esum,
                            int2* __restrict__ csr_pack) {
    __shared__ int sp[SCAN_BS];
    int pv = (threadIdx.x < NBLK) ? partial[threadIdx.x] : 0;
    sp[threadIdx.x] = pv;
    __syncthreads();
    for (int off = 1; off < SCAN_BS; off <<= 1) {
        int t = (threadIdx.x >= off) ? sp[threadIdx.x - off] : 0;
        __syncthreads();
        sp[threadIdx.x] += t;
        __syncthreads();
    }
    float es = 0.f;
    #pragma unroll
    for (int jj = 0; jj < 32; ++jj) es += esum[jj * PAD];
    int base = (blockIdx.x == 0) ? 0 : sp[blockIdx.x - 1];
    int i = blockIdx.x * SCAN_BS + threadIdx.x;
    if (i < N_NODES) {
        int r = row_start[i] + base;
        row_start[i] = r;
        csr_pack[r] = make_int2(i, __float_as_int(es * (1.0f / N_EDGES)));
        cursor[i] = r + 1;
    }
    if (i == 0) row_start[N_NODES] = E2;
}

// ===== pass B (r2 rewrite): slice-owned scatter, no global atomics.
// Old version: 1.6M global cursor atomics (avg 32 hits/address, ~1000/line)
// serialized at the memory-side atomic units (VALUBusy 0.6%, 77us) and
// scattered 8B stores gave 4.5x write amplification (WRITE_SIZE 59MB vs
// 13MB ideal). Now: each block owns 128 nodes' cursors in LDS (seeded from
// row_start+1) and filter-scans its bucket's staged edges. LDS atomics are
// ~cycles; each csr_pack line is written whole by one block (amp -> ~1x).
// Cost: 16x redundant bucket reads = 200MB of L2 traffic (~6us) — cheap.
// Grid 32x16: bucket = blockIdx&31, so all 16 slice-blocks of bucket b sit
// on XCD b%8 and share its L2 copy of the staged bucket.
__global__ void scatter_slice(const int2* __restrict__ stg,
                              const int* __restrict__ bcursor,
                              const int* __restrict__ row_start,
                              int2* __restrict__ csr_pack) {
    __shared__ int lcur[SLICE_W];
    int b = blockIdx.x & 31;
    int m = blockIdx.x >> 5;
    if (b >= NB) return;
    int nbase = (b << BSH) + m * SLICE_W;
    for (int i = threadIdx.x; i < SLICE_W; i += 256) {
        int node = nbase + i;
        lcur[i] = (node < N_NODES) ? row_start[node] + 1 : 0;  // +1 skips self-loop slot
    }
    __syncthreads();
    int n = bcursor[b * PAD];
    const int2* sd = stg + (size_t)b * CAP;
    int lo = m * SLICE_W, hi = lo + SLICE_W;
    for (int idx = threadIdx.x; idx < n; idx += 256) {
        int2 e = sd[idx];
        int dl = (e.x >> 16) & 2047;
        if (dl >= lo && dl < hi) {
            int q = atomicAdd(&lcur[dl - lo], 1);
            csr_pack[q] = make_int2(e.x & 0xFFFF, e.y);
        }
    }
}

// ---- xl = x@Wl + bl ; xr = x@Wr + br -> fp16 outputs.
// r1 rewrite (verified): LDS-stage the x tile, compute reads LDS broadcast.
template<int K>
__global__ __launch_bounds__(256) void linear_dual_k(
                              const float* __restrict__ x,
                              const float* __restrict__ Wl, const float* __restrict__ bl,
                              const float* __restrict__ Wr, const float* __restrict__ br,
                              __half* __restrict__ xl, __half* __restrict__ xr) {
    const int TN = 64;            // nodes per block
    const int NPW = TN / 4;       // 16 nodes per wave
    __shared__ float xs[TN * K];  // 32KB (K=128) / 16KB (K=64)
    int t = threadIdx.x;
    int nb = blockIdx.x * TN;
    int rem = N_NODES - nb;
    int tot4 = (rem >= TN ? TN : rem) * (K / 4);
    const float4* xg = (const float4*)(x + (size_t)nb * K);
    float4* xs4 = (float4*)xs;
    for (int i = t; i < tot4; i += 256) xs4[i] = xg[i];
    __syncthreads();
    int wave = t >> 6, d = t & 63;
    int n0 = wave * NPW;
    float blv = bl[d], brv = br[d];
    float al[NPW], ar[NPW];
    #pragma unroll
    for (int i = 0; i < NPW; ++i) { al[i] = blv; ar[i] = brv; }
    #pragma unroll 2
    for (int k4 = 0; k4 < K / 4; ++k4) {
        int kb = k4 * 4;
        float wl[4], wr[4];
        #pragma unroll
        for (int q = 0; q < 4; ++q) {
            wl[q] = Wl[(kb + q) * D_H + d];
            wr[q] = Wr[(kb + q) * D_H + d];
        }
        #pragma unroll
        for (int i = 0; i < NPW; ++i) {
            float4 xv = *(const float4*)&xs[(n0 + i) * K + kb];  // LDS broadcast
            al[i] = fmaf(xv.x, wl[0], al[i]);
            al[i] = fmaf(xv.y, wl[1], al[i]);
            al[i] = fmaf(xv.z, wl[2], al[i]);
            al[i] = fmaf(xv.w, wl[3], al[i]);
            ar[i] = fmaf(xv.x, wr[0], ar[i]);
            ar[i] = fmaf(xv.y, wr[1], ar[i]);
            ar[i] = fmaf(xv.z, wr[2], ar[i]);
            ar[i] = fmaf(xv.w, wr[3], ar[i]);
        }
    }
    #pragma unroll
    for (int i = 0; i < NPW; ++i) {
        int g = nb + n0 + i;
        if (g < N_NODES) {
            xl[(size_t)g * D_H + d] = __float2half(al[i]);
            xr[(size_t)g * D_H + d] = __float2half(ar[i]);
        }
    }
}

// ---- fused GATv2 layer, 16-lane-group layout, 16 edges/iter, fp16 gathers.
// No running max (logits O(10), fp32 exp overflow at 88, shift-invariant).
__global__ void gat_fused(const int* __restrict__ row_start, const int2* __restrict__ csr_pack,
                          const __half* __restrict__ xl, const __half* __restrict__ xr,
                          const float* __restrict__ We, const float* __restrict__ att,
                          const float* __restrict__ b, float* __restrict__ out) {
    int node = blockIdx.x * (blockDim.x >> 6) + (threadIdx.x >> 6);
    if (node >= N_NODES) return;
    int lane = threadIdx.x & 63;
    int g = lane >> 4;
    int s = lane & 15;
    int fb = s * 4;
    float4 we4  = *(const float4*)(We + fb);
    float4 att4 = *(const float4*)(att + fb);
    float4 xr4  = ld_h4(xr + (size_t)node * D_H + fb);
    int j0 = row_start[node], j1 = row_start[node + 1];

    float S = 0.f;
    float4 acc = make_float4(0.f, 0.f, 0.f, 0.f);

    for (int base = j0; base < j1; base += 16) {
        int i0 = base + 4 * g;
        bool v0 = i0 < j1, v1 = i0 + 1 < j1, v2 = i0 + 2 < j1, v3 = i0 + 3 < j1;
        int c0 = v0 ? i0 : j0, c1 = v1 ? i0 + 1 : j0;
        int c2 = v2 ? i0 + 2 : j0, c3 = v3 ? i0 + 3 : j0;
        int2 p0 = csr_pack[c0], p1 = csr_pack[c1], p2 = csr_pack[c2], p3 = csr_pack[c3];
        float4 r0 = ld_h4(xl + (size_t)p0.x * D_H + fb);
        float4 r1 = ld_h4(xl + (size_t)p1.x * D_H + fb);
        float4 r2 = ld_h4(xl + (size_t)p2.x * D_H + fb);
        float4 r3 = ld_h4(xl + (size_t)p3.x * D_H + fb);
        float e0 = __int_as_float(p0.y), e1 = __int_as_float(p1.y);
        float e2 = __int_as_float(p2.y), e3 = __int_as_float(p3.y);

        float t0, t1, t2, t3;
        {
            float4 v;
            v.x = fmaf(e0, we4.x, r0.x + xr4.x); v.y = fmaf(e0, we4.y, r0.y + xr4.y);
            v.z = fmaf(e0, we4.z, r0.z + xr4.z); v.w = fmaf(e0, we4.w, r0.w + xr4.w);
            v.x = fmaxf(v.x, NEG_SLOPE * v.x); v.y = fmaxf(v.y, NEG_SLOPE * v.y);
            v.z = fmaxf(v.z, NEG_SLOPE * v.z); v.w = fmaxf(v.w, NEG_SLOPE * v.w);
            t0 = fmaf(v.w, att4.w, fmaf(v.z, att4.z, fmaf(v.y, att4.y, v.x * att4.x)));
            v.x = fmaf(e1, we4.x, r1.x + xr4.x); v.y = fmaf(e1, we4.y, r1.y + xr4.y);
            v.z = fmaf(e1, we4.z, r1.z + xr4.z); v.w = fmaf(e1, we4.w, r1.w + xr4.w);
            v.x = fmaxf(v.x, NEG_SLOPE * v.x); v.y = fmaxf(v.y, NEG_SLOPE * v.y);
            v.z = fmaxf(v.z, NEG_SLOPE * v.z); v.w = fmaxf(v.w, NEG_SLOPE * v.w);
            t1 = fmaf(v.w, att4.w, fmaf(v.z, att4.z, fmaf(v.y, att4.y, v.x * att4.x)));
            v.x = fmaf(e2, we4.x, r2.x + xr4.x); v.y = fmaf(e2, we4.y, r2.y + xr4.y);
            v.z = fmaf(e2, we4.z, r2.z + xr4.z); v.w = fmaf(e2, we4.w, r2.w + xr4.w);
            v.x = fmaxf(v.x, NEG_SLOPE * v.x); v.y = fmaxf(v.y, NEG_SLOPE * v.y);
            v.z = fmaxf(v.z, NEG_SLOPE * v.z); v.w = fmaxf(v.w, NEG_SLOPE * v.w);
            t2 = fmaf(v.w, att4.w, fmaf(v.z, att4.z, fmaf(v.y, att4.y, v.x * att4.x)));
            v.x = fmaf(e3, we4.x, r3.x + xr4.x); v.y = fmaf(e3, we4.y, r3.y + xr4.y);
            v.z = fmaf(e3, we4.z, r3.z + xr4.z); v.w = fmaf(e3, we4.w, r3.w + xr4.w);
            v.x = fmaxf(v.x, NEG_SLOPE * v.x); v.y = fmaxf(v.y, NEG_SLOPE * v.y);
            v.z = fmaxf(v.z, NEG_SLOPE * v.z); v.w = fmaxf(v.w, NEG_SLOPE * v.w);
            t3 = fmaf(v.w, att4.w, fmaf(v.z, att4.z, fmaf(v.y, att4.y, v.x * att4.x)));
        }
        #pragma unroll
        for (int off = 1; off <= 8; off <<= 1) {   // stays inside the 16-lane group
            t0 += __shfl_xor(t0, off);
            t1 += __shfl_xor(t1, off);
            t2 += __shfl_xor(t2, off);
            t3 += __shfl_xor(t3, off);
        }
        float z0 = v0 ? __expf(t0) : 0.f;
        float z1 = v1 ? __expf(t1) : 0.f;
        float z2 = v2 ? __expf(t2) : 0.f;
        float z3 = v3 ? __expf(t3) : 0.f;
        S += (z0 + z1) + (z2 + z3);
        acc.x = fmaf(z3, r3.x, fmaf(z2, r2.x, fmaf(z1, r1.x, fmaf(z0, r0.x, acc.x))));
        acc.y = fmaf(z3, r3.y, fmaf(z2, r2.y, fmaf(z1, r1.y, fmaf(z0, r0.y, acc.y))));
        acc.z = fmaf(z3, r3.z, fmaf(z2, r2.z, fmaf(z1, r1.z, fmaf(z0, r0.z, acc.z))));
        acc.w = fmaf(z3, r3.w, fmaf(z2, r2.w, fmaf(z1, r1.w, fmaf(z0, r0.w, acc.w))));
    }

    // plain sum-merge of the 4 groups (xor 16, then xor 32)
    #pragma unroll
    for (int off = 16; off <= 32; off <<= 1) {
        S     += __shfl_xor(S, off);
        acc.x += __shfl_xor(acc.x, off);
        acc.y += __shfl_xor(acc.y, off);
        acc.z += __shfl_xor(acc.z, off);
        acc.w += __shfl_xor(acc.w, off);
    }

    if (g == 0) {
        float4 b4 = *(const float4*)(b + fb);
        float inv = 1.f / (S + 1e-16f);
        float4 h;
        h.x = fmaf(acc.x, inv, b4.x);
        h.y = fmaf(acc.y, inv, b4.y);
        h.z = fmaf(acc.z, inv, b4.z);
        h.w = fmaf(acc.w, inv, b4.w);
        h.x = h.x > 0.f ? h.x : expm1f(h.x);
        h.y = h.y > 0.f ? h.y : expm1f(h.y);
        h.z = h.z > 0.f ? h.z : expm1f(h.z);
        h.w = h.w > 0.f ? h.w : expm1f(h.w);
        *(float4*)(out + (size_t)node * D_H + fb) = h;
    }
}

// ---- global mean pool (batch is sorted): register accumulate, flush on change
__global__ void pool(const float* __restrict__ h, const int* __restrict__ batch,
                     float* __restrict__ pooled, float* __restrict__ counts) {
    const int CHUNK = 128;
    int base = blockIdx.x * CHUNK;
    int d = threadIdx.x;  // blockDim = 64
    float accv = 0.f; int cur_g = -1; int cnt = 0;
    for (int i = 0; i < CHUNK; ++i) {
        int n = base + i;
        if (n >= N_NODES) break;
        int g = batch[n];
        if (g != cur_g) {
            if (cur_g >= 0) {
                atomicAdd(&pooled[cur_g * D_H + d], accv);
                if (d == 0) atomicAdd(&counts[cur_g], (float)cnt);
            }
            cur_g = g; accv = 0.f; cnt = 0;
        }
        accv += h[(size_t)n * D_H + d];
        cnt++;
    }
    if (cur_g >= 0) {
        atomicAdd(&pooled[cur_g * D_H + d], accv);
        if (d == 0) atomicAdd(&counts[cur_g], (float)cnt);
    }
}

__global__ void classify(const float* __restrict__ pooled, const float* __restrict__ counts,
                         const float* __restrict__ Wc, const float* __restrict__ bc,
                         float* __restrict__ out) {
    int tid = threadIdx.x;             // 640 threads
    int g = tid / N_CLS, c = tid % N_CLS;
    if (g >= N_GRAPHS) return;
    float inv = 1.0f / fmaxf(counts[g], 1.0f);
    float a = bc[c];
    for (int k = 0; k < D_H; ++k)
        a = fmaf(pooled[g * D_H + k] * inv, Wc[k * N_CLS + c], a);
    out[g * N_CLS + c] = a;
}

extern "C" void kernel_launch(void* const* d_in, const int* in_sizes, int n_in,
                              void* d_out, int out_size, void* d_ws, size_t ws_size,
                              hipStream_t stream) {
    const float* x     = (const float*)d_in[0];
    const int*   ei    = (const int*)d_in[1];
    const float* eattr = (const float*)d_in[2];
    const int*   batch = (const int*)d_in[3];
    const float *Wl1 = (const float*)d_in[4],  *bl1 = (const float*)d_in[5];
    const float *Wr1 = (const float*)d_in[6],  *br1 = (const float*)d_in[7];
    const float *We1 = (const float*)d_in[8],  *att1 = (const float*)d_in[9];
    const float *b1  = (const float*)d_in[10];
    const float *Wl2 = (const float*)d_in[11], *bl2 = (const float*)d_in[12];
    const float *Wr2 = (const float*)d_in[13], *br2 = (const float*)d_in[14];
    const float *We2 = (const float*)d_in[15], *att2 = (const float*)d_in[16];
    const float *b2  = (const float*)d_in[17];
    const float *Wc  = (const float*)d_in[18], *bc = (const float*)d_in[19];
    float* out = (float*)d_out;

    const int* src = ei;
    const int* dst = ei + N_EDGES;

    // workspace layout. stg (int2, 15.36 MB) is dead after scatter; xl/xr (fp16,
    // 6.4 MB each) + h (fp32, 12.8 MB) = 25.6 MB alias its region. csr_pack kept
    // at the old 30.72 MB offset so it stays clear of xl/xr/h.
    char* base = (char*)d_ws;
    int2*  stg     = (int2*)base;                       // NB*CAP*8B = 15.36 MB
    __half* xl     = (__half*)base;                     // N*64 fp16 (6.4 MB)
    __half* xr     = xl + (size_t)N_NODES * D_H;        // N*64 fp16
    float* h       = (float*)(xr + (size_t)N_NODES * D_H); // N*64 fp32 (12.8 MB)
    int2*  csr_pack = (int2*)(base + (size_t)NB * CAP * 16); // E2 (8B) = 13.2 MB
    int*   row_start = (int*)(csr_pack + E2);           // N+1
    int*   cnt     = row_start + N_NODES + 1;           // N
    float* esum    = (float*)(cnt + N_NODES);           // 32 lines (32*PAD floats)
    int*   bcursor = (int*)(esum + 32 * PAD);           // NB lines (NB*PAD ints)
    int*   cursor  = bcursor + NB * PAD;                // N
    int*   partial = cursor + N_NODES;                  // NBLK
    float* pooled  = (float*)(partial + NBLK);          // 64*64
    float* counts  = pooled + N_GRAPHS * D_H;           // 64

    const int WPB = 4;  // waves per block at 256 threads
    int node_wave_blocks = (N_NODES + WPB - 1) / WPB;
    int lin_blocks = (N_NODES + 63) / 64;               // 64 nodes per block

    hipMemsetAsync(cnt, 0, (N_NODES + 32 * PAD + NB * PAD) * sizeof(int), stream);
    hipMemsetAsync(pooled, 0, (N_GRAPHS * D_H + N_GRAPHS) * sizeof(float), stream);

    // ---- CSR build: stage -> LDS hist -> scan -> slice-scatter ----
    bucket_stage<<<(N_EDGES / EPT + 255) / 256, 256, 0, stream>>>(
        src, dst, eattr, esum, bcursor, stg);
    hist_bucket<<<NB * HBB, 256, 0, stream>>>(stg, bcursor, cnt);
    scan_block<<<NBLK, SCAN_BS, 0, stream>>>(cnt, row_start, partial);
    add_offsets<<<NBLK, SCAN_BS, 0, stream>>>(row_start, partial, cursor, esum, csr_pack);
    scatter_slice<<<SLICES * 32, 256, 0, stream>>>(stg, bcursor, row_start, csr_pack);

    // ---------------- layer 1 ----------------
    linear_dual_k<D_IN><<<lin_blocks, 256, 0, stream>>>(x, Wl1, bl1, Wr1, br1, xl, xr);
    gat_fused<<<node_wave_blocks, 256, 0, stream>>>(row_start, csr_pack, xl, xr, We1, att1, b1, h);

    // ---------------- layer 2 ----------------
    linear_dual_k<D_H><<<lin_blocks, 256, 0, stream>>>(h, Wl2, bl2, Wr2, br2, xl, xr);
    gat_fused<<<node_wave_blocks, 256, 0, stream>>>(row_start, csr_pack, xl, xr, We2, att2, b2, h);

    // ---------------- pool + classify ----------------
    pool<<<(N_NODES + 127) / 128, 64, 0, stream>>>(h, batch, pooled, counts);
    classify<<<1, 640, 0, stream>>>(pooled, counts, Wc, bc, out);
}

// Round 4
// 386.760 us; speedup vs baseline: 1.4838x; 1.1745x over previous
//
#include <hip/hip_runtime.h>
#include <hip/hip_fp16.h>
#include <math.h>

#define N_NODES 50000
#define N_EDGES 1600000
#define D_IN 128
#define D_H 64
#define N_CLS 10
#define N_GRAPHS 64
#define NEG_SLOPE 0.2f
#define E2 (N_EDGES + N_NODES)   // edges + self loops
#define SCAN_BS 256
#define NBLK ((N_NODES + SCAN_BS - 1) / SCAN_BS)   // 196 <= 256

// bucketed scatter params
#define NB 25                 // buckets: dst >> 11 (50000/2048 -> 0..24)
#define BSH 11
#define CAP 76800             // per-bucket staging capacity (>40 sigma over E/NB)
#define HBB 8                 // hist blocks per bucket
#define EPT 8                 // edges/thread in bucket_stage
#define PAD 32                // 128B stride: one cache line per contended counter
#define SLICES 8              // node-slices per bucket in scatter_slice
#define SLICE_W (2048 / SLICES)   // 256 nodes per slice

__device__ inline float wave_reduce_sum(float v) {
    for (int off = 32; off; off >>= 1) v += __shfl_xor(v, off);
    return v;
}

// one 8B load -> 4 floats from fp16 row chunk
__device__ inline float4 ld_h4(const __half* p) {
    int2 raw = *(const int2*)p;
    __half2 a = *(__half2*)&raw.x;
    __half2 b = *(__half2*)&raw.y;
    return make_float4(__low2float(a), __high2float(a), __low2float(b), __high2float(b));
}

// ===== pass A: bucket-stage edges + eattr sum.
// r0 fix (verified): contended-line atomics were the serializer. esum spread
// over 32 lines, bcursor one line per bucket, EPT=8, int2 staging.
__global__ void bucket_stage(const int* __restrict__ src, const int* __restrict__ dst,
                             const float* __restrict__ eattr,
                             float* esum, int* bcursor,
                             int2* __restrict__ stg) {
    __shared__ int bcnt[4][32];
    __shared__ int woff[4][32];
    __shared__ float esh[4];
    int t = threadIdx.x;
    int wave = t >> 6;
    if (t < 128) bcnt[t >> 5][t & 31] = 0;
    __syncthreads();
    int e0 = (blockIdx.x * blockDim.x + t) * EPT;   // N_EDGES % EPT == 0
    int ss[EPT], tt[EPT], aa[EPT], r[EPT], b[EPT];
    float v = 0.f;
    bool valid = e0 < N_EDGES;
    if (valid) {
        #pragma unroll
        for (int q = 0; q < EPT / 4; ++q) {
            int4 s4 = *(const int4*)(src + e0 + 4 * q);
            int4 t4 = *(const int4*)(dst + e0 + 4 * q);
            float4 a4 = *(const float4*)(eattr + e0 + 4 * q);
            ss[4*q] = s4.x; ss[4*q+1] = s4.y; ss[4*q+2] = s4.z; ss[4*q+3] = s4.w;
            tt[4*q] = t4.x; tt[4*q+1] = t4.y; tt[4*q+2] = t4.z; tt[4*q+3] = t4.w;
            aa[4*q]   = __float_as_int(a4.x); aa[4*q+1] = __float_as_int(a4.y);
            aa[4*q+2] = __float_as_int(a4.z); aa[4*q+3] = __float_as_int(a4.w);
            v += (a4.x + a4.y) + (a4.z + a4.w);
        }
        #pragma unroll
        for (int i = 0; i < EPT; ++i) {
            b[i] = tt[i] >> BSH;
            r[i] = atomicAdd(&bcnt[wave][b[i]], 1);
        }
    }
    v = wave_reduce_sum(v);
    if ((t & 63) == 0) esh[wave] = v;
    __syncthreads();
    if (t < NB) {
        int c0 = bcnt[0][t], c1 = bcnt[1][t], c2 = bcnt[2][t], c3 = bcnt[3][t];
        int tot = c0 + c1 + c2 + c3;
        int base = tot ? atomicAdd(&bcursor[t * PAD], tot) : 0;
        woff[0][t] = base;
        woff[1][t] = base + c0;
        woff[2][t] = base + c0 + c1;
        woff[3][t] = base + c0 + c1 + c2;
    }
    if (t == 0) {
        float tot = (esh[0] + esh[1]) + (esh[2] + esh[3]);
        atomicAdd(&esum[(blockIdx.x & 31) * PAD], tot);   // 32 distinct lines
    }
    __syncthreads();
    if (valid) {
        #pragma unroll
        for (int i = 0; i < EPT; ++i) {
            int p = b[i] * CAP + woff[wave][b[i]] + r[i];
            stg[p] = make_int2((ss[i] & 0xFFFF) | ((tt[i] & 2047) << 16), aa[i]);
        }
    }
}

// ===== pass A2: per-node histogram from staged dst-low bits, LDS-resident window
__global__ void hist_bucket(const int2* __restrict__ stg, const int* __restrict__ bcursor,
                            int* cnt) {
    __shared__ int hist[2048];
    int b = blockIdx.x / HBB;
    int j = blockIdx.x % HBB;
    for (int i = threadIdx.x; i < 2048; i += 256) hist[i] = 0;
    __syncthreads();
    int n = bcursor[b * PAD];
    const int2* sd = stg + (size_t)b * CAP;
    int per = (n + HBB - 1) / HBB;
    int start = j * per;
    int end = min(start + per, n);
    for (int idx = start + threadIdx.x; idx < end; idx += 256)
        atomicAdd(&hist[(sd[idx].x >> 16) & 2047], 1);
    __syncthreads();
    int nb = b << BSH;
    for (int i = threadIdx.x; i < 2048; i += 256) {
        int c = hist[i];
        if (c) atomicAdd(&cnt[nb + i], c);
    }
}

// ---- block-local exclusive scan; +1 per node folds in the self-loop slot ----
__global__ void scan_block(const int* __restrict__ cnt, int* __restrict__ row_start,
                           int* __restrict__ partial) {
    __shared__ int sd[SCAN_BS];
    int i = blockIdx.x * SCAN_BS + threadIdx.x;
    int v = (i < N_NODES) ? (cnt[i] + 1) : 0;   // +1 = self loop
    sd[threadIdx.x] = v;
    __syncthreads();
    for (int off = 1; off < SCAN_BS; off <<= 1) {
        int t = (threadIdx.x >= off) ? sd[threadIdx.x - off] : 0;
        __syncthreads();
        sd[threadIdx.x] += t;
        __syncthreads();
    }
    if (i < N_NODES) row_start[i] = sd[threadIdx.x] - v;
    if (threadIdx.x == SCAN_BS - 1) partial[blockIdx.x] = sd[threadIdx.x];
}
// finalize row_start (redundant LDS scan of partials replaces a launch),
// write self-loop CSR entry, seed cursor
__global__ void add_offsets(int* __restrict__ row_start, const int* __restrict__ partial,
                            int* __restrict__ cursor, const float* __restrict__ esum,
                            int2* __restrict__ csr_pack) {
    __shared__ int sp[SCAN_BS];
    int pv = (threadIdx.x < NBLK) ? partial[threadIdx.x] : 0;
    sp[threadIdx.x] = pv;
    __syncthreads();
    for (int off = 1; off < SCAN_BS; off <<= 1) {
        int t = (threadIdx.x >= off) ? sp[threadIdx.x - off] : 0;
        __syncthreads();
        sp[threadIdx.x] += t;
        __syncthreads();
    }
    float es = 0.f;
    #pragma unroll
    for (int jj = 0; jj < 32; ++jj) es += esum[jj * PAD];
    int base = (blockIdx.x == 0) ? 0 : sp[blockIdx.x - 1];
    int i = blockIdx.x * SCAN_BS + threadIdx.x;
    if (i < N_NODES) {
        int r = row_start[i] + base;
        row_start[i] = r;
        csr_pack[r] = make_int2(i, __float_as_int(es * (1.0f / N_EDGES)));
        cursor[i] = r + 1;
    }
    if (i == 0) row_start[N_NODES] = E2;
}

// ===== pass B (r3 re-tune of the r2 slice-scatter).
// r2 post-mortem: slice ownership fixed write-amp (59->15MB, verified) but
// dur went 77->89us: 512 blocks = 2/CU = 8 waves/CU (Occupancy 16%) each
// running 250 serial {8B L2 load -> dependent filter} iterations — latency-
// bound, 11x above the L2-BW floor. Fix the latency hiding, keep the
// algorithm: SLICES 8 (halves redundant reads), 1024-thread blocks (16
// waves/CU), int4 loads (2 edges each) with 4 independent loads in flight
// per iteration (interleaved-coalesced: each instruction reads 1KB/wave).
// Grid 32x8: bucket = blockIdx&31 -> all 8 slice-blocks of bucket b land on
// XCD b%8 and share that L2's copy of the staged bucket (~13MB/XCD ~ 3us).
__global__ __launch_bounds__(1024) void scatter_slice(
                              const int2* __restrict__ stg,
                              const int* __restrict__ bcursor,
                              const int* __restrict__ row_start,
                              int2* __restrict__ csr_pack) {
    __shared__ int lcur[SLICE_W];
    int b = blockIdx.x & 31;
    int m = blockIdx.x >> 5;
    if (b >= NB) return;
    int nbase = (b << BSH) + m * SLICE_W;
    for (int i = threadIdx.x; i < SLICE_W; i += 1024) {
        int node = nbase + i;
        lcur[i] = (node < N_NODES) ? row_start[node] + 1 : 0;  // +1 skips self-loop slot
    }
    __syncthreads();
    int n = bcursor[b * PAD];
    const int4* sd4 = (const int4*)(stg + (size_t)b * CAP);   // b*CAP*8B is 16B-aligned
    int n4 = n >> 1;
    int lo = m * SLICE_W, hi = lo + SLICE_W;
    for (int base4 = 0; base4 < n4; base4 += 4096) {
        int4 e[4];
        int idx[4];
        #pragma unroll
        for (int j = 0; j < 4; ++j) {
            idx[j] = base4 + j * 1024 + (int)threadIdx.x;
            if (idx[j] < n4) e[j] = sd4[idx[j]];
        }
        #pragma unroll
        for (int j = 0; j < 4; ++j) {
            if (idx[j] < n4) {
                int dl0 = (e[j].x >> 16) & 2047;
                if (dl0 >= lo && dl0 < hi) {
                    int q = atomicAdd(&lcur[dl0 - lo], 1);
                    csr_pack[q] = make_int2(e[j].x & 0xFFFF, e[j].y);
                }
                int dl1 = (e[j].z >> 16) & 2047;
                if (dl1 >= lo && dl1 < hi) {
                    int q = atomicAdd(&lcur[dl1 - lo], 1);
                    csr_pack[q] = make_int2(e[j].z & 0xFFFF, e[j].w);
                }
            }
        }
    }
    if ((n & 1) && threadIdx.x == 0) {   // odd tail edge; only owning slice stores
        int2 e = stg[(size_t)b * CAP + n - 1];
        int dl = (e.x >> 16) & 2047;
        if (dl >= lo && dl < hi) {
            int q = atomicAdd(&lcur[dl - lo], 1);
            csr_pack[q] = make_int2(e.x & 0xFFFF, e.y);
        }
    }
}

// ---- xl = x@Wl + bl ; xr = x@Wr + br -> fp16 outputs.
// r1 rewrite (verified): LDS-stage the x tile, compute reads LDS broadcast.
template<int K>
__global__ __launch_bounds__(256) void linear_dual_k(
                              const float* __restrict__ x,
                              const float* __restrict__ Wl, const float* __restrict__ bl,
                              const float* __restrict__ Wr, const float* __restrict__ br,
                              __half* __restrict__ xl, __half* __restrict__ xr) {
    const int TN = 64;            // nodes per block
    const int NPW = TN / 4;       // 16 nodes per wave
    __shared__ float xs[TN * K];  // 32KB (K=128) / 16KB (K=64)
    int t = threadIdx.x;
    int nb = blockIdx.x * TN;
    int rem = N_NODES - nb;
    int tot4 = (rem >= TN ? TN : rem) * (K / 4);
    const float4* xg = (const float4*)(x + (size_t)nb * K);
    float4* xs4 = (float4*)xs;
    for (int i = t; i < tot4; i += 256) xs4[i] = xg[i];
    __syncthreads();
    int wave = t >> 6, d = t & 63;
    int n0 = wave * NPW;
    float blv = bl[d], brv = br[d];
    float al[NPW], ar[NPW];
    #pragma unroll
    for (int i = 0; i < NPW; ++i) { al[i] = blv; ar[i] = brv; }
    #pragma unroll 2
    for (int k4 = 0; k4 < K / 4; ++k4) {
        int kb = k4 * 4;
        float wl[4], wr[4];
        #pragma unroll
        for (int q = 0; q < 4; ++q) {
            wl[q] = Wl[(kb + q) * D_H + d];
            wr[q] = Wr[(kb + q) * D_H + d];
        }
        #pragma unroll
        for (int i = 0; i < NPW; ++i) {
            float4 xv = *(const float4*)&xs[(n0 + i) * K + kb];  // LDS broadcast
            al[i] = fmaf(xv.x, wl[0], al[i]);
            al[i] = fmaf(xv.y, wl[1], al[i]);
            al[i] = fmaf(xv.z, wl[2], al[i]);
            al[i] = fmaf(xv.w, wl[3], al[i]);
            ar[i] = fmaf(xv.x, wr[0], ar[i]);
            ar[i] = fmaf(xv.y, wr[1], ar[i]);
            ar[i] = fmaf(xv.z, wr[2], ar[i]);
            ar[i] = fmaf(xv.w, wr[3], ar[i]);
        }
    }
    #pragma unroll
    for (int i = 0; i < NPW; ++i) {
        int g = nb + n0 + i;
        if (g < N_NODES) {
            xl[(size_t)g * D_H + d] = __float2half(al[i]);
            xr[(size_t)g * D_H + d] = __float2half(ar[i]);
        }
    }
}

// ---- fused GATv2 layer, 16-lane-group layout, 16 edges/iter, fp16 gathers.
// No running max (logits O(10), fp32 exp overflow at 88, shift-invariant).
__global__ void gat_fused(const int* __restrict__ row_start, const int2* __restrict__ csr_pack,
                          const __half* __restrict__ xl, const __half* __restrict__ xr,
                          const float* __restrict__ We, const float* __restrict__ att,
                          const float* __restrict__ b, float* __restrict__ out) {
    int node = blockIdx.x * (blockDim.x >> 6) + (threadIdx.x >> 6);
    if (node >= N_NODES) return;
    int lane = threadIdx.x & 63;
    int g = lane >> 4;
    int s = lane & 15;
    int fb = s * 4;
    float4 we4  = *(const float4*)(We + fb);
    float4 att4 = *(const float4*)(att + fb);
    float4 xr4  = ld_h4(xr + (size_t)node * D_H + fb);
    int j0 = row_start[node], j1 = row_start[node + 1];

    float S = 0.f;
    float4 acc = make_float4(0.f, 0.f, 0.f, 0.f);

    for (int base = j0; base < j1; base += 16) {
        int i0 = base + 4 * g;
        bool v0 = i0 < j1, v1 = i0 + 1 < j1, v2 = i0 + 2 < j1, v3 = i0 + 3 < j1;
        int c0 = v0 ? i0 : j0, c1 = v1 ? i0 + 1 : j0;
        int c2 = v2 ? i0 + 2 : j0, c3 = v3 ? i0 + 3 : j0;
        int2 p0 = csr_pack[c0], p1 = csr_pack[c1], p2 = csr_pack[c2], p3 = csr_pack[c3];
        float4 r0 = ld_h4(xl + (size_t)p0.x * D_H + fb);
        float4 r1 = ld_h4(xl + (size_t)p1.x * D_H + fb);
        float4 r2 = ld_h4(xl + (size_t)p2.x * D_H + fb);
        float4 r3 = ld_h4(xl + (size_t)p3.x * D_H + fb);
        float e0 = __int_as_float(p0.y), e1 = __int_as_float(p1.y);
        float e2 = __int_as_float(p2.y), e3 = __int_as_float(p3.y);

        float t0, t1, t2, t3;
        {
            float4 v;
            v.x = fmaf(e0, we4.x, r0.x + xr4.x); v.y = fmaf(e0, we4.y, r0.y + xr4.y);
            v.z = fmaf(e0, we4.z, r0.z + xr4.z); v.w = fmaf(e0, we4.w, r0.w + xr4.w);
            v.x = fmaxf(v.x, NEG_SLOPE * v.x); v.y = fmaxf(v.y, NEG_SLOPE * v.y);
            v.z = fmaxf(v.z, NEG_SLOPE * v.z); v.w = fmaxf(v.w, NEG_SLOPE * v.w);
            t0 = fmaf(v.w, att4.w, fmaf(v.z, att4.z, fmaf(v.y, att4.y, v.x * att4.x)));
            v.x = fmaf(e1, we4.x, r1.x + xr4.x); v.y = fmaf(e1, we4.y, r1.y + xr4.y);
            v.z = fmaf(e1, we4.z, r1.z + xr4.z); v.w = fmaf(e1, we4.w, r1.w + xr4.w);
            v.x = fmaxf(v.x, NEG_SLOPE * v.x); v.y = fmaxf(v.y, NEG_SLOPE * v.y);
            v.z = fmaxf(v.z, NEG_SLOPE * v.z); v.w = fmaxf(v.w, NEG_SLOPE * v.w);
            t1 = fmaf(v.w, att4.w, fmaf(v.z, att4.z, fmaf(v.y, att4.y, v.x * att4.x)));
            v.x = fmaf(e2, we4.x, r2.x + xr4.x); v.y = fmaf(e2, we4.y, r2.y + xr4.y);
            v.z = fmaf(e2, we4.z, r2.z + xr4.z); v.w = fmaf(e2, we4.w, r2.w + xr4.w);
            v.x = fmaxf(v.x, NEG_SLOPE * v.x); v.y = fmaxf(v.y, NEG_SLOPE * v.y);
            v.z = fmaxf(v.z, NEG_SLOPE * v.z); v.w = fmaxf(v.w, NEG_SLOPE * v.w);
            t2 = fmaf(v.w, att4.w, fmaf(v.z, att4.z, fmaf(v.y, att4.y, v.x * att4.x)));
            v.x = fmaf(e3, we4.x, r3.x + xr4.x); v.y = fmaf(e3, we4.y, r3.y + xr4.y);
            v.z = fmaf(e3, we4.z, r3.z + xr4.z); v.w = fmaf(e3, we4.w, r3.w + xr4.w);
            v.x = fmaxf(v.x, NEG_SLOPE * v.x); v.y = fmaxf(v.y, NEG_SLOPE * v.y);
            v.z = fmaxf(v.z, NEG_SLOPE * v.z); v.w = fmaxf(v.w, NEG_SLOPE * v.w);
            t3 = fmaf(v.w, att4.w, fmaf(v.z, att4.z, fmaf(v.y, att4.y, v.x * att4.x)));
        }
        #pragma unroll
        for (int off = 1; off <= 8; off <<= 1) {   // stays inside the 16-lane group
            t0 += __shfl_xor(t0, off);
            t1 += __shfl_xor(t1, off);
            t2 += __shfl_xor(t2, off);
            t3 += __shfl_xor(t3, off);
        }
        float z0 = v0 ? __expf(t0) : 0.f;
        float z1 = v1 ? __expf(t1) : 0.f;
        float z2 = v2 ? __expf(t2) : 0.f;
        float z3 = v3 ? __expf(t3) : 0.f;
        S += (z0 + z1) + (z2 + z3);
        acc.x = fmaf(z3, r3.x, fmaf(z2, r2.x, fmaf(z1, r1.x, fmaf(z0, r0.x, acc.x))));
        acc.y = fmaf(z3, r3.y, fmaf(z2, r2.y, fmaf(z1, r1.y, fmaf(z0, r0.y, acc.y))));
        acc.z = fmaf(z3, r3.z, fmaf(z2, r2.z, fmaf(z1, r1.z, fmaf(z0, r0.z, acc.z))));
        acc.w = fmaf(z3, r3.w, fmaf(z2, r2.w, fmaf(z1, r1.w, fmaf(z0, r0.w, acc.w))));
    }

    // plain sum-merge of the 4 groups (xor 16, then xor 32)
    #pragma unroll
    for (int off = 16; off <= 32; off <<= 1) {
        S     += __shfl_xor(S, off);
        acc.x += __shfl_xor(acc.x, off);
        acc.y += __shfl_xor(acc.y, off);
        acc.z += __shfl_xor(acc.z, off);
        acc.w += __shfl_xor(acc.w, off);
    }

    if (g == 0) {
        float4 b4 = *(const float4*)(b + fb);
        float inv = 1.f / (S + 1e-16f);
        float4 h;
        h.x = fmaf(acc.x, inv, b4.x);
        h.y = fmaf(acc.y, inv, b4.y);
        h.z = fmaf(acc.z, inv, b4.z);
        h.w = fmaf(acc.w, inv, b4.w);
        h.x = h.x > 0.f ? h.x : expm1f(h.x);
        h.y = h.y > 0.f ? h.y : expm1f(h.y);
        h.z = h.z > 0.f ? h.z : expm1f(h.z);
        h.w = h.w > 0.f ? h.w : expm1f(h.w);
        *(float4*)(out + (size_t)node * D_H + fb) = h;
    }
}

// ---- global mean pool (batch is sorted): register accumulate, flush on change
__global__ void pool(const float* __restrict__ h, const int* __restrict__ batch,
                     float* __restrict__ pooled, float* __restrict__ counts) {
    const int CHUNK = 128;
    int base = blockIdx.x * CHUNK;
    int d = threadIdx.x;  // blockDim = 64
    float accv = 0.f; int cur_g = -1; int cnt = 0;
    for (int i = 0; i < CHUNK; ++i) {
        int n = base + i;
        if (n >= N_NODES) break;
        int g = batch[n];
        if (g != cur_g) {
            if (cur_g >= 0) {
                atomicAdd(&pooled[cur_g * D_H + d], accv);
                if (d == 0) atomicAdd(&counts[cur_g], (float)cnt);
            }
            cur_g = g; accv = 0.f; cnt = 0;
        }
        accv += h[(size_t)n * D_H + d];
        cnt++;
    }
    if (cur_g >= 0) {
        atomicAdd(&pooled[cur_g * D_H + d], accv);
        if (d == 0) atomicAdd(&counts[cur_g], (float)cnt);
    }
}

__global__ void classify(const float* __restrict__ pooled, const float* __restrict__ counts,
                         const float* __restrict__ Wc, const float* __restrict__ bc,
                         float* __restrict__ out) {
    int tid = threadIdx.x;             // 640 threads
    int g = tid / N_CLS, c = tid % N_CLS;
    if (g >= N_GRAPHS) return;
    float inv = 1.0f / fmaxf(counts[g], 1.0f);
    float a = bc[c];
    for (int k = 0; k < D_H; ++k)
        a = fmaf(pooled[g * D_H + k] * inv, Wc[k * N_CLS + c], a);
    out[g * N_CLS + c] = a;
}

extern "C" void kernel_launch(void* const* d_in, const int* in_sizes, int n_in,
                              void* d_out, int out_size, void* d_ws, size_t ws_size,
                              hipStream_t stream) {
    const float* x     = (const float*)d_in[0];
    const int*   ei    = (const int*)d_in[1];
    const float* eattr = (const float*)d_in[2];
    const int*   batch = (const int*)d_in[3];
    const float *Wl1 = (const float*)d_in[4],  *bl1 = (const float*)d_in[5];
    const float *Wr1 = (const float*)d_in[6],  *br1 = (const float*)d_in[7];
    const float *We1 = (const float*)d_in[8],  *att1 = (const float*)d_in[9];
    const float *b1  = (const float*)d_in[10];
    const float *Wl2 = (const float*)d_in[11], *bl2 = (const float*)d_in[12];
    const float *Wr2 = (const float*)d_in[13], *br2 = (const float*)d_in[14];
    const float *We2 = (const float*)d_in[15], *att2 = (const float*)d_in[16];
    const float *b2  = (const float*)d_in[17];
    const float *Wc  = (const float*)d_in[18], *bc = (const float*)d_in[19];
    float* out = (float*)d_out;

    const int* src = ei;
    const int* dst = ei + N_EDGES;

    // workspace layout. stg (int2, 15.36 MB) is dead after scatter; xl/xr (fp16,
    // 6.4 MB each) + h (fp32, 12.8 MB) = 25.6 MB alias its region. csr_pack kept
    // at the old 30.72 MB offset so it stays clear of xl/xr/h.
    char* base = (char*)d_ws;
    int2*  stg     = (int2*)base;                       // NB*CAP*8B = 15.36 MB
    __half* xl     = (__half*)base;                     // N*64 fp16 (6.4 MB)
    __half* xr     = xl + (size_t)N_NODES * D_H;        // N*64 fp16
    float* h       = (float*)(xr + (size_t)N_NODES * D_H); // N*64 fp32 (12.8 MB)
    int2*  csr_pack = (int2*)(base + (size_t)NB * CAP * 16); // E2 (8B) = 13.2 MB
    int*   row_start = (int*)(csr_pack + E2);           // N+1
    int*   cnt     = row_start + N_NODES + 1;           // N
    float* esum    = (float*)(cnt + N_NODES);           // 32 lines (32*PAD floats)
    int*   bcursor = (int*)(esum + 32 * PAD);           // NB lines (NB*PAD ints)
    int*   cursor  = bcursor + NB * PAD;                // N
    int*   partial = cursor + N_NODES;                  // NBLK
    float* pooled  = (float*)(partial + NBLK);          // 64*64
    float* counts  = pooled + N_GRAPHS * D_H;           // 64

    const int WPB = 4;  // waves per block at 256 threads
    int node_wave_blocks = (N_NODES + WPB - 1) / WPB;
    int lin_blocks = (N_NODES + 63) / 64;               // 64 nodes per block

    hipMemsetAsync(cnt, 0, (N_NODES + 32 * PAD + NB * PAD) * sizeof(int), stream);
    hipMemsetAsync(pooled, 0, (N_GRAPHS * D_H + N_GRAPHS) * sizeof(float), stream);

    // ---- CSR build: stage -> LDS hist -> scan -> slice-scatter ----
    bucket_stage<<<(N_EDGES / EPT + 255) / 256, 256, 0, stream>>>(
        src, dst, eattr, esum, bcursor, stg);
    hist_bucket<<<NB * HBB, 256, 0, stream>>>(stg, bcursor, cnt);
    scan_block<<<NBLK, SCAN_BS, 0, stream>>>(cnt, row_start, partial);
    add_offsets<<<NBLK, SCAN_BS, 0, stream>>>(row_start, partial, cursor, esum, csr_pack);
    scatter_slice<<<SLICES * 32, 1024, 0, stream>>>(stg, bcursor, row_start, csr_pack);

    // ---------------- layer 1 ----------------
    linear_dual_k<D_IN><<<lin_blocks, 256, 0, stream>>>(x, Wl1, bl1, Wr1, br1, xl, xr);
    gat_fused<<<node_wave_blocks, 256, 0, stream>>>(row_start, csr_pack, xl, xr, We1, att1, b1, h);

    // ---------------- layer 2 ----------------
    linear_dual_k<D_H><<<lin_blocks, 256, 0, stream>>>(h, Wl2, bl2, Wr2, br2, xl, xr);
    gat_fused<<<node_wave_blocks, 256, 0, stream>>>(row_start, csr_pack, xl, xr, We2, att2, b2, h);

    // ---------------- pool + classify ----------------
    pool<<<(N_NODES + 127) / 128, 64, 0, stream>>>(h, batch, pooled, counts);
    classify<<<1, 640, 0, stream>>>(pooled, counts, Wc, bc, out);
}

// Round 7
// 367.422 us; speedup vs baseline: 1.5619x; 1.0526x over previous
//
#include <hip/hip_runtime.h>
#include <hip/hip_fp16.h>
#include <math.h>

#define N_NODES 50000
#define N_EDGES 1600000
#define D_IN 128
#define D_H 64
#define N_CLS 10
#define N_GRAPHS 64
#define NEG_SLOPE 0.2f
#define E2 (N_EDGES + N_NODES)   // edges + self loops
#define SCAN_BS 256
#define NBLK ((N_NODES + SCAN_BS - 1) / SCAN_BS)   // 196 <= 256

// bucketed scatter params
#define NB 25                 // buckets: dst >> 11 (50000/2048 -> 0..24)
#define BSH 11
#define CAP 76800             // per-bucket staging capacity (>40 sigma over E/NB)
#define HBB 8                 // hist blocks per bucket
#define EPT 8                 // edges/thread in bucket_stage
#define PAD 32                // 128B stride: one cache line per contended counter
#define SLICES 8              // node-slices per bucket in scatter_slice
#define SLICE_W (2048 / SLICES)   // 256 nodes per slice

// packed fp16 via clang ext_vector — plain operators lower to v_pk_*_f16.
// (r5 lesson: ROCm 7.2 hip_fp16.h has NO __hmax2/__hmul2 half2 intrinsics.)
typedef _Float16 f16x2 __attribute__((ext_vector_type(2)));

__device__ inline f16x2 as_h2(unsigned u) { return __builtin_bit_cast(f16x2, u); }
__device__ inline int h2_as_int(f16x2 v) { return __builtin_bit_cast(int, v); }

__device__ inline f16x2 pk_leaky(f16x2 m, f16x2 ns) {
#if __has_builtin(__builtin_elementwise_max)
    return __builtin_elementwise_max(m, m * ns);
#else
    f16x2 p = m * ns, r;
    r.x = m.x > p.x ? m.x : p.x;
    r.y = m.y > p.y ? m.y : p.y;
    return r;
#endif
}

#if __has_builtin(__builtin_amdgcn_fdot2)
__device__ inline float fdot2a(f16x2 a, f16x2 b, float c) {
    return __builtin_amdgcn_fdot2(a, b, c, false);
}
#else
__device__ inline float fdot2a(f16x2 a, f16x2 b, float c) {
    return fmaf((float)a.x, (float)b.x, fmaf((float)a.y, (float)b.y, c));
}
#endif

__device__ inline float wave_reduce_sum(float v) {
    for (int off = 32; off; off >>= 1) v += __shfl_xor(v, off);
    return v;
}

// ===== pass A: bucket-stage edges + eattr sum.
// r0 fix (verified): contended-line atomics were the serializer. esum spread
// over 32 lines, bcursor one line per bucket, EPT=8, int2 staging.
// r4: eattr staged as half2(a,a) so gat's hot loop needs no per-edge cvt.
__global__ void bucket_stage(const int* __restrict__ src, const int* __restrict__ dst,
                             const float* __restrict__ eattr,
                             float* esum, int* bcursor,
                             int2* __restrict__ stg) {
    __shared__ int bcnt[4][32];
    __shared__ int woff[4][32];
    __shared__ float esh[4];
    int t = threadIdx.x;
    int wave = t >> 6;
    if (t < 128) bcnt[t >> 5][t & 31] = 0;
    __syncthreads();
    int e0 = (blockIdx.x * blockDim.x + t) * EPT;   // N_EDGES % EPT == 0
    int ss[EPT], tt[EPT], aa[EPT], r[EPT], b[EPT];
    float v = 0.f;
    bool valid = e0 < N_EDGES;
    if (valid) {
        #pragma unroll
        for (int q = 0; q < EPT / 4; ++q) {
            int4 s4 = *(const int4*)(src + e0 + 4 * q);
            int4 t4 = *(const int4*)(dst + e0 + 4 * q);
            float4 a4 = *(const float4*)(eattr + e0 + 4 * q);
            ss[4*q] = s4.x; ss[4*q+1] = s4.y; ss[4*q+2] = s4.z; ss[4*q+3] = s4.w;
            tt[4*q] = t4.x; tt[4*q+1] = t4.y; tt[4*q+2] = t4.z; tt[4*q+3] = t4.w;
            aa[4*q]   = h2_as_int((f16x2){(_Float16)a4.x, (_Float16)a4.x});
            aa[4*q+1] = h2_as_int((f16x2){(_Float16)a4.y, (_Float16)a4.y});
            aa[4*q+2] = h2_as_int((f16x2){(_Float16)a4.z, (_Float16)a4.z});
            aa[4*q+3] = h2_as_int((f16x2){(_Float16)a4.w, (_Float16)a4.w});
            v += (a4.x + a4.y) + (a4.z + a4.w);
        }
        #pragma unroll
        for (int i = 0; i < EPT; ++i) {
            b[i] = tt[i] >> BSH;
            r[i] = atomicAdd(&bcnt[wave][b[i]], 1);
        }
    }
    v = wave_reduce_sum(v);
    if ((t & 63) == 0) esh[wave] = v;
    __syncthreads();
    if (t < NB) {
        int c0 = bcnt[0][t], c1 = bcnt[1][t], c2 = bcnt[2][t], c3 = bcnt[3][t];
        int tot = c0 + c1 + c2 + c3;
        int base = tot ? atomicAdd(&bcursor[t * PAD], tot) : 0;
        woff[0][t] = base;
        woff[1][t] = base + c0;
        woff[2][t] = base + c0 + c1;
        woff[3][t] = base + c0 + c1 + c2;
    }
    if (t == 0) {
        float tot = (esh[0] + esh[1]) + (esh[2] + esh[3]);
        atomicAdd(&esum[(blockIdx.x & 31) * PAD], tot);   // 32 distinct lines
    }
    __syncthreads();
    if (valid) {
        #pragma unroll
        for (int i = 0; i < EPT; ++i) {
            int p = b[i] * CAP + woff[wave][b[i]] + r[i];
            stg[p] = make_int2((ss[i] & 0xFFFF) | ((tt[i] & 2047) << 16), aa[i]);
        }
    }
}

// ===== pass A2: per-node histogram from staged dst-low bits, LDS-resident window
__global__ void hist_bucket(const int2* __restrict__ stg, const int* __restrict__ bcursor,
                            int* cnt) {
    __shared__ int hist[2048];
    int b = blockIdx.x / HBB;
    int j = blockIdx.x % HBB;
    for (int i = threadIdx.x; i < 2048; i += 256) hist[i] = 0;
    __syncthreads();
    int n = bcursor[b * PAD];
    const int2* sd = stg + (size_t)b * CAP;
    int per = (n + HBB - 1) / HBB;
    int start = j * per;
    int end = min(start + per, n);
    for (int idx = start + threadIdx.x; idx < end; idx += 256)
        atomicAdd(&hist[(sd[idx].x >> 16) & 2047], 1);
    __syncthreads();
    int nb = b << BSH;
    for (int i = threadIdx.x; i < 2048; i += 256) {
        int c = hist[i];
        if (c) atomicAdd(&cnt[nb + i], c);
    }
}

// ---- block-local exclusive scan; +1 per node folds in the self-loop slot ----
__global__ void scan_block(const int* __restrict__ cnt, int* __restrict__ row_start,
                           int* __restrict__ partial) {
    __shared__ int sd[SCAN_BS];
    int i = blockIdx.x * SCAN_BS + threadIdx.x;
    int v = (i < N_NODES) ? (cnt[i] + 1) : 0;   // +1 = self loop
    sd[threadIdx.x] = v;
    __syncthreads();
    for (int off = 1; off < SCAN_BS; off <<= 1) {
        int t = (threadIdx.x >= off) ? sd[threadIdx.x - off] : 0;
        __syncthreads();
        sd[threadIdx.x] += t;
        __syncthreads();
    }
    if (i < N_NODES) row_start[i] = sd[threadIdx.x] - v;
    if (threadIdx.x == SCAN_BS - 1) partial[blockIdx.x] = sd[threadIdx.x];
}
// finalize row_start (redundant LDS scan of partials replaces a launch),
// write self-loop CSR entry (eattr-mean as half2), seed cursor
__global__ void add_offsets(int* __restrict__ row_start, const int* __restrict__ partial,
                            int* __restrict__ cursor, const float* __restrict__ esum,
                            int2* __restrict__ csr_pack) {
    __shared__ int sp[SCAN_BS];
    int pv = (threadIdx.x < NBLK) ? partial[threadIdx.x] : 0;
    sp[threadIdx.x] = pv;
    __syncthreads();
    for (int off = 1; off < SCAN_BS; off <<= 1) {
        int t = (threadIdx.x >= off) ? sp[threadIdx.x - off] : 0;
        __syncthreads();
        sp[threadIdx.x] += t;
        __syncthreads();
    }
    float es = 0.f;
    #pragma unroll
    for (int jj = 0; jj < 32; ++jj) es += esum[jj * PAD];
    float esm = es * (1.0f / N_EDGES);
    int ebits = h2_as_int((f16x2){(_Float16)esm, (_Float16)esm});
    int base = (blockIdx.x == 0) ? 0 : sp[blockIdx.x - 1];
    int i = blockIdx.x * SCAN_BS + threadIdx.x;
    if (i < N_NODES) {
        int r = row_start[i] + base;
        row_start[i] = r;
        csr_pack[r] = make_int2(i, ebits);
        cursor[i] = r + 1;
    }
    if (i == 0) row_start[N_NODES] = E2;
}

// ===== pass B (r3-verified): slice-owned scatter, LDS cursors, deep MLP.
__global__ __launch_bounds__(1024) void scatter_slice(
                              const int2* __restrict__ stg,
                              const int* __restrict__ bcursor,
                              const int* __restrict__ row_start,
                              int2* __restrict__ csr_pack) {
    __shared__ int lcur[SLICE_W];
    int b = blockIdx.x & 31;
    int m = blockIdx.x >> 5;
    if (b >= NB) return;
    int nbase = (b << BSH) + m * SLICE_W;
    for (int i = threadIdx.x; i < SLICE_W; i += 1024) {
        int node = nbase + i;
        lcur[i] = (node < N_NODES) ? row_start[node] + 1 : 0;  // +1 skips self-loop slot
    }
    __syncthreads();
    int n = bcursor[b * PAD];
    const int4* sd4 = (const int4*)(stg + (size_t)b * CAP);   // b*CAP*8B is 16B-aligned
    int n4 = n >> 1;
    int lo = m * SLICE_W, hi = lo + SLICE_W;
    for (int base4 = 0; base4 < n4; base4 += 4096) {
        int4 e[4];
        int idx[4];
        #pragma unroll
        for (int j = 0; j < 4; ++j) {
            idx[j] = base4 + j * 1024 + (int)threadIdx.x;
            if (idx[j] < n4) e[j] = sd4[idx[j]];
        }
        #pragma unroll
        for (int j = 0; j < 4; ++j) {
            if (idx[j] < n4) {
                int dl0 = (e[j].x >> 16) & 2047;
                if (dl0 >= lo && dl0 < hi) {
                    int q = atomicAdd(&lcur[dl0 - lo], 1);
                    csr_pack[q] = make_int2(e[j].x & 0xFFFF, e[j].y);
                }
                int dl1 = (e[j].z >> 16) & 2047;
                if (dl1 >= lo && dl1 < hi) {
                    int q = atomicAdd(&lcur[dl1 - lo], 1);
                    csr_pack[q] = make_int2(e[j].z & 0xFFFF, e[j].w);
                }
            }
        }
    }
    if ((n & 1) && threadIdx.x == 0) {   // odd tail edge; only owning slice stores
        int2 e = stg[(size_t)b * CAP + n - 1];
        int dl = (e.x >> 16) & 2047;
        if (dl >= lo && dl < hi) {
            int q = atomicAdd(&lcur[dl - lo], 1);
            csr_pack[q] = make_int2(e.x & 0xFFFF, e.y);
        }
    }
}

// ---- xl = x@Wl + bl ; xr = x@Wr + br -> fp16 outputs.
// r1 rewrite (verified): LDS-stage the x tile, compute reads LDS broadcast.
template<int K>
__global__ __launch_bounds__(256) void linear_dual_k(
                              const float* __restrict__ x,
                              const float* __restrict__ Wl, const float* __restrict__ bl,
                              const float* __restrict__ Wr, const float* __restrict__ br,
                              __half* __restrict__ xl, __half* __restrict__ xr) {
    const int TN = 64;            // nodes per block
    const int NPW = TN / 4;       // 16 nodes per wave
    __shared__ float xs[TN * K];  // 32KB (K=128) / 16KB (K=64)
    int t = threadIdx.x;
    int nb = blockIdx.x * TN;
    int rem = N_NODES - nb;
    int tot4 = (rem >= TN ? TN : rem) * (K / 4);
    const float4* xg = (const float4*)(x + (size_t)nb * K);
    float4* xs4 = (float4*)xs;
    for (int i = t; i < tot4; i += 256) xs4[i] = xg[i];
    __syncthreads();
    int wave = t >> 6, d = t & 63;
    int n0 = wave * NPW;
    float blv = bl[d], brv = br[d];
    float al[NPW], ar[NPW];
    #pragma unroll
    for (int i = 0; i < NPW; ++i) { al[i] = blv; ar[i] = brv; }
    #pragma unroll 2
    for (int k4 = 0; k4 < K / 4; ++k4) {
        int kb = k4 * 4;
        float wl[4], wr[4];
        #pragma unroll
        for (int q = 0; q < 4; ++q) {
            wl[q] = Wl[(kb + q) * D_H + d];
            wr[q] = Wr[(kb + q) * D_H + d];
        }
        #pragma unroll
        for (int i = 0; i < NPW; ++i) {
            float4 xv = *(const float4*)&xs[(n0 + i) * K + kb];  // LDS broadcast
            al[i] = fmaf(xv.x, wl[0], al[i]);
            al[i] = fmaf(xv.y, wl[1], al[i]);
            al[i] = fmaf(xv.z, wl[2], al[i]);
            al[i] = fmaf(xv.w, wl[3], al[i]);
            ar[i] = fmaf(xv.x, wr[0], ar[i]);
            ar[i] = fmaf(xv.y, wr[1], ar[i]);
            ar[i] = fmaf(xv.z, wr[2], ar[i]);
            ar[i] = fmaf(xv.w, wr[3], ar[i]);
        }
    }
    #pragma unroll
    for (int i = 0; i < NPW; ++i) {
        int g = nb + n0 + i;
        if (g < N_NODES) {
            xl[(size_t)g * D_H + d] = __float2half(al[i]);
            xr[(size_t)g * D_H + d] = __float2half(ar[i]);
        }
    }
}

// ---- fused GATv2 layer — r4 design (r6: ext_vector operators only, no __h*2).
// r4 theory: kernel was VALU-bound (VALUBusy 89-93%, HBM 17%). Cuts:
//   (a) one NODE per 16-lane group (4 nodes/wave, 4-edge granularity):
//       less padding waste on avg-deg-33 rows; no cross-group merge; every
//       lane writes output (no g==0-only epilogue).
//   (b) packed fp16 message math: f16x2 operators (v_pk_fma/add/mul) +
//       elementwise_max leaky-relu + v_dot2_f32_f16 att-dot (fp32 accum).
//       Output acc stays fp32 via mix-fma. eattr pre-packed half2(a,a) in
//       csr_pack.y (bucket_stage/add_offsets).
// No running max (logits O(10), fp32 exp overflow at 88, shift-invariant).
__global__ __launch_bounds__(256) void gat_fused(
        const int* __restrict__ row_start, const int2* __restrict__ csr_pack,
        const __half* __restrict__ xl, const __half* __restrict__ xr,
        const float* __restrict__ We, const float* __restrict__ att,
        const float* __restrict__ b, float* __restrict__ out) {
    int lane = threadIdx.x & 63;
    int g = lane >> 4;
    int s = lane & 15;
    int wid = blockIdx.x * (blockDim.x >> 6) + (threadIdx.x >> 6);
    int node = wid * 4 + g;                 // 16 nodes per 256-thread block
    bool nv = node < N_NODES;
    int nodec = nv ? node : 0;
    int fb = s * 4;
    float4 we4  = *(const float4*)(We + fb);
    float4 att4 = *(const float4*)(att + fb);
    f16x2 we0 = {(_Float16)we4.x, (_Float16)we4.y};
    f16x2 we1 = {(_Float16)we4.z, (_Float16)we4.w};
    f16x2 at0 = {(_Float16)att4.x, (_Float16)att4.y};
    f16x2 at1 = {(_Float16)att4.z, (_Float16)att4.w};
    uint2 xru = *(const uint2*)(xr + (size_t)nodec * D_H + fb);
    f16x2 xr0 = as_h2(xru.x), xr1 = as_h2(xru.y);
    const f16x2 ns = {(_Float16)NEG_SLOPE, (_Float16)NEG_SLOPE};
    int j0 = 0, j1 = 0;
    if (nv) { j0 = row_start[node]; j1 = row_start[node + 1]; }

    float S = 0.f;
    float4 acc = make_float4(0.f, 0.f, 0.f, 0.f);

    for (int i0 = j0; i0 < j1; i0 += 4) {   // same trip count across each 16-lane group
        int2 pk[4]; uint2 qk[4]; bool vk[4];
        #pragma unroll
        for (int k = 0; k < 4; ++k) {
            vk[k] = (i0 + k) < j1;
            int c = vk[k] ? (i0 + k) : i0;
            pk[k] = csr_pack[c];
        }
        #pragma unroll
        for (int k = 0; k < 4; ++k)
            qk[k] = *(const uint2*)(xl + (size_t)pk[k].x * D_H + fb);
        float t[4]; f16x2 rl[4], rh[4];
        #pragma unroll
        for (int k = 0; k < 4; ++k) {
            rl[k] = as_h2(qk[k].x);
            rh[k] = as_h2(qk[k].y);
            f16x2 a2 = as_h2((unsigned)pk[k].y);
            f16x2 m0 = a2 * we0 + (rl[k] + xr0);   // v_pk_fma + v_pk_add
            f16x2 m1 = a2 * we1 + (rh[k] + xr1);
            m0 = pk_leaky(m0, ns);                 // packed leaky relu
            m1 = pk_leaky(m1, ns);
            t[k] = fdot2a(m1, at1, fdot2a(m0, at0, 0.f));  // fp32 accum
        }
        #pragma unroll
        for (int off = 1; off <= 8; off <<= 1) {   // reduce within 16-lane group
            t[0] += __shfl_xor(t[0], off);
            t[1] += __shfl_xor(t[1], off);
            t[2] += __shfl_xor(t[2], off);
            t[3] += __shfl_xor(t[3], off);
        }
        float z[4];
        #pragma unroll
        for (int k = 0; k < 4; ++k)
            z[k] = vk[k] ? __expf(t[k]) : 0.f;
        S += (z[0] + z[1]) + (z[2] + z[3]);
        #pragma unroll
        for (int k = 0; k < 4; ++k) {              // fp32 acc via mix-fma
            acc.x = fmaf(z[k], (float)rl[k].x, acc.x);
            acc.y = fmaf(z[k], (float)rl[k].y, acc.y);
            acc.z = fmaf(z[k], (float)rh[k].x, acc.z);
            acc.w = fmaf(z[k], (float)rh[k].y, acc.w);
        }
    }

    if (nv) {
        float4 b4 = *(const float4*)(b + fb);
        float inv = 1.f / (S + 1e-16f);
        float4 h;
        h.x = fmaf(acc.x, inv, b4.x);
        h.y = fmaf(acc.y, inv, b4.y);
        h.z = fmaf(acc.z, inv, b4.z);
        h.w = fmaf(acc.w, inv, b4.w);
        h.x = h.x > 0.f ? h.x : expm1f(h.x);
        h.y = h.y > 0.f ? h.y : expm1f(h.y);
        h.z = h.z > 0.f ? h.z : expm1f(h.z);
        h.w = h.w > 0.f ? h.w : expm1f(h.w);
        *(float4*)(out + (size_t)node * D_H + fb) = h;
    }
}

// ---- global mean pool (batch is sorted): register accumulate, flush on change
__global__ void pool(const float* __restrict__ h, const int* __restrict__ batch,
                     float* __restrict__ pooled, float* __restrict__ counts) {
    const int CHUNK = 128;
    int base = blockIdx.x * CHUNK;
    int d = threadIdx.x;  // blockDim = 64
    float accv = 0.f; int cur_g = -1; int cnt = 0;
    for (int i = 0; i < CHUNK; ++i) {
        int n = base + i;
        if (n >= N_NODES) break;
        int g = batch[n];
        if (g != cur_g) {
            if (cur_g >= 0) {
                atomicAdd(&pooled[cur_g * D_H + d], accv);
                if (d == 0) atomicAdd(&counts[cur_g], (float)cnt);
            }
            cur_g = g; accv = 0.f; cnt = 0;
        }
        accv += h[(size_t)n * D_H + d];
        cnt++;
    }
    if (cur_g >= 0) {
        atomicAdd(&pooled[cur_g * D_H + d], accv);
        if (d == 0) atomicAdd(&counts[cur_g], (float)cnt);
    }
}

__global__ void classify(const float* __restrict__ pooled, const float* __restrict__ counts,
                         const float* __restrict__ Wc, const float* __restrict__ bc,
                         float* __restrict__ out) {
    int tid = threadIdx.x;             // 640 threads
    int g = tid / N_CLS, c = tid % N_CLS;
    if (g >= N_GRAPHS) return;
    float inv = 1.0f / fmaxf(counts[g], 1.0f);
    float a = bc[c];
    for (int k = 0; k < D_H; ++k)
        a = fmaf(pooled[g * D_H + k] * inv, Wc[k * N_CLS + c], a);
    out[g * N_CLS + c] = a;
}

extern "C" void kernel_launch(void* const* d_in, const int* in_sizes, int n_in,
                              void* d_out, int out_size, void* d_ws, size_t ws_size,
                              hipStream_t stream) {
    const float* x     = (const float*)d_in[0];
    const int*   ei    = (const int*)d_in[1];
    const float* eattr = (const float*)d_in[2];
    const int*   batch = (const int*)d_in[3];
    const float *Wl1 = (const float*)d_in[4],  *bl1 = (const float*)d_in[5];
    const float *Wr1 = (const float*)d_in[6],  *br1 = (const float*)d_in[7];
    const float *We1 = (const float*)d_in[8],  *att1 = (const float*)d_in[9];
    const float *b1  = (const float*)d_in[10];
    const float *Wl2 = (const float*)d_in[11], *bl2 = (const float*)d_in[12];
    const float *Wr2 = (const float*)d_in[13], *br2 = (const float*)d_in[14];
    const float *We2 = (const float*)d_in[15], *att2 = (const float*)d_in[16];
    const float *b2  = (const float*)d_in[17];
    const float *Wc  = (const float*)d_in[18], *bc = (const float*)d_in[19];
    float* out = (float*)d_out;

    const int* src = ei;
    const int* dst = ei + N_EDGES;

    // workspace layout. stg (int2, 15.36 MB) is dead after scatter; xl/xr (fp16,
    // 6.4 MB each) + h (fp32, 12.8 MB) = 25.6 MB alias its region. csr_pack kept
    // at the old 30.72 MB offset so it stays clear of xl/xr/h.
    char* base = (char*)d_ws;
    int2*  stg     = (int2*)base;                       // NB*CAP*8B = 15.36 MB
    __half* xl     = (__half*)base;                     // N*64 fp16 (6.4 MB)
    __half* xr     = xl + (size_t)N_NODES * D_H;        // N*64 fp16
    float* h       = (float*)(xr + (size_t)N_NODES * D_H); // N*64 fp32 (12.8 MB)
    int2*  csr_pack = (int2*)(base + (size_t)NB * CAP * 16); // E2 (8B) = 13.2 MB
    int*   row_start = (int*)(csr_pack + E2);           // N+1
    int*   cnt     = row_start + N_NODES + 1;           // N
    float* esum    = (float*)(cnt + N_NODES);           // 32 lines (32*PAD floats)
    int*   bcursor = (int*)(esum + 32 * PAD);           // NB lines (NB*PAD ints)
    int*   cursor  = bcursor + NB * PAD;                // N
    int*   partial = cursor + N_NODES;                  // NBLK
    float* pooled  = (float*)(partial + NBLK);          // 64*64
    float* counts  = pooled + N_GRAPHS * D_H;           // 64

    int gat_blocks = (N_NODES + 15) / 16;               // 16 nodes per 256-thr block
    int lin_blocks = (N_NODES + 63) / 64;               // 64 nodes per block

    hipMemsetAsync(cnt, 0, (N_NODES + 32 * PAD + NB * PAD) * sizeof(int), stream);
    hipMemsetAsync(pooled, 0, (N_GRAPHS * D_H + N_GRAPHS) * sizeof(float), stream);

    // ---- CSR build: stage -> LDS hist -> scan -> slice-scatter ----
    bucket_stage<<<(N_EDGES / EPT + 255) / 256, 256, 0, stream>>>(
        src, dst, eattr, esum, bcursor, stg);
    hist_bucket<<<NB * HBB, 256, 0, stream>>>(stg, bcursor, cnt);
    scan_block<<<NBLK, SCAN_BS, 0, stream>>>(cnt, row_start, partial);
    add_offsets<<<NBLK, SCAN_BS, 0, stream>>>(row_start, partial, cursor, esum, csr_pack);
    scatter_slice<<<SLICES * 32, 1024, 0, stream>>>(stg, bcursor, row_start, csr_pack);

    // ---------------- layer 1 ----------------
    linear_dual_k<D_IN><<<lin_blocks, 256, 0, stream>>>(x, Wl1, bl1, Wr1, br1, xl, xr);
    gat_fused<<<gat_blocks, 256, 0, stream>>>(row_start, csr_pack, xl, xr, We1, att1, b1, h);

    // ---------------- layer 2 ----------------
    linear_dual_k<D_H><<<lin_blocks, 256, 0, stream>>>(h, Wl2, bl2, Wr2, br2, xl, xr);
    gat_fused<<<gat_blocks, 256, 0, stream>>>(row_start, csr_pack, xl, xr, We2, att2, b2, h);

    // ---------------- pool + classify ----------------
    pool<<<(N_NODES + 127) / 128, 64, 0, stream>>>(h, batch, pooled, counts);
    classify<<<1, 640, 0, stream>>>(pooled, counts, Wc, bc, out);
}